// Round 1
// 261.399 us; speedup vs baseline: 1.0035x; 1.0035x over previous
//
#include <hip/hip_runtime.h>
#include <cstdint>
#include <cstddef>

typedef __attribute__((ext_vector_type(8))) short short8;
typedef __attribute__((ext_vector_type(8))) unsigned short ushort8;
typedef __attribute__((ext_vector_type(4))) float f32x4;
typedef __attribute__((ext_vector_type(8))) _Float16 half8;
typedef __attribute__((ext_vector_type(4))) _Float16 half4;
typedef __attribute__((ext_vector_type(2))) __fp16 fp16x2;

#define DEV static __device__ __forceinline__

DEV unsigned short f2bf(float x) {
  union { float f; unsigned u; } v; v.f = x;
  unsigned r = v.u + 0x7fffu + ((v.u >> 16) & 1u);
  return (unsigned short)(r >> 16);
}
DEV float bf2f(unsigned short u) {
  union { unsigned u; float f; } v; v.u = ((unsigned)u) << 16;
  return v.f;
}
DEV unsigned pack2bf(float lo, float hi) {
  union { float f; unsigned u; } a, b; a.f = lo; b.f = hi;
  return __builtin_amdgcn_perm(b.u + 0x8000u, a.u + 0x8000u, 0x07060302u);
}
DEV f32x4 mfma16(short8 a, short8 b, f32x4 c) {
  return __builtin_amdgcn_mfma_f32_16x16x32_bf16(a, b, c, 0, 0, 0);
}
DEV f32x4 mfma16h(half8 a, half8 b, f32x4 c) {
  return __builtin_amdgcn_mfma_f32_16x16x32_f16(a, b, c, 0, 0, 0);
}
DEV f32x4 mfma16k(half4 a, half4 b, f32x4 c) {
  return __builtin_amdgcn_mfma_f32_16x16x16f16(a, b, c, 0, 0, 0);
}

// async global->LDS, 16B per lane; LDS dst = wave-uniform base + lane*16
typedef __attribute__((address_space(1))) unsigned int g_u32;
typedef __attribute__((address_space(3))) unsigned int l_u32;
DEV void glds16(const unsigned short* g, unsigned short* l) {
  __builtin_amdgcn_global_load_lds((g_u32*)g, (l_u32*)l, 16, 0, 0);
}

constexpr int Bc = 4, Nc = 2048, Dc = 1024, Hc = 16, DKc = 16, DVc = 64, DIc = 1280;
constexpr int Mc = Bc * Nc;  // 8192

// ---------------- elementwise fp32 -> bf16 ----------------
__global__ __launch_bounds__(256) void convert_x(const float* __restrict__ X,
                                                 unsigned short* __restrict__ Xb, int total8) {
  int i = blockIdx.x * 256 + threadIdx.x;
  if (i >= total8) return;
  const float4* p = (const float4*)(X + (size_t)i * 8);
  float4 a = p[0], b = p[1];
  ushort8 o;
  o[0] = f2bf(a.x); o[1] = f2bf(a.y); o[2] = f2bf(a.z); o[3] = f2bf(a.w);
  o[4] = f2bf(b.x); o[5] = f2bf(b.y); o[6] = f2bf(b.z); o[7] = f2bf(b.w);
  *(ushort8*)(Xb + (size_t)i * 8) = o;
}

// ---------------- W[K][N] fp32 -> WT[N][K] bf16 ----------------
__global__ __launch_bounds__(256) void transpose_convert(const float* __restrict__ W,
                                                         unsigned short* __restrict__ WT,
                                                         int K, int N) {
  __shared__ unsigned short t[64][72];
  int k0 = blockIdx.x * 64, n0 = blockIdx.y * 64;
  int tid = threadIdx.x;
#pragma unroll
  for (int it = 0; it < 16; ++it) {
    int f = it * 256 + tid;
    int r = f >> 6, c = f & 63;
    t[c][r] = f2bf(W[(size_t)(k0 + r) * N + n0 + c]);
  }
  __syncthreads();
#pragma unroll
  for (int it = 0; it < 16; ++it) {
    int f = it * 256 + tid;
    int r = f >> 6, c = f & 63;
    WT[(size_t)(n0 + r) * K + k0 + c] = t[r][c];
  }
}

// ---------------- fused projection GEMM: C = Xbf * [WqgT | WkvT]^T ----------------
__global__ __launch_bounds__(256) void gemm_proj(const unsigned short* __restrict__ A,
                                                 const unsigned short* __restrict__ BT,
                                                 unsigned short* __restrict__ QG,
                                                 unsigned short* __restrict__ KV,
                                                 int Kq) {
  __shared__ unsigned short As[128 * 64];
  __shared__ unsigned short Bs[128 * 64];
  int row0 = blockIdx.x * 128, col0 = blockIdx.y * 128;
  int tid = threadIdx.x, lane = tid & 63, wave = tid >> 6;
  int wm = wave >> 1, wn = wave & 1;
  int ql = lane >> 4, l16 = lane & 15;
  int r8 = lane >> 3, cbl = (lane & 7) ^ r8;

  unsigned short* dst = (col0 >= DIc) ? KV : QG;
  int c0l = (col0 >= DIc) ? col0 - DIc : col0;

  const unsigned short* gA = A + (size_t)(row0 + wave * 32 + r8) * Kq + cbl * 8;
  const unsigned short* gB = BT + (size_t)(col0 + wave * 32 + r8) * Kq + cbl * 8;

  f32x4 acc[4][4];
#pragma unroll
  for (int i = 0; i < 4; i++)
#pragma unroll
    for (int j = 0; j < 4; j++) acc[i][j] = (f32x4){0.f, 0.f, 0.f, 0.f};

  for (int k0 = 0; k0 < Kq; k0 += 64) {
    __syncthreads();
#pragma unroll
    for (int i = 0; i < 4; ++i) {
      glds16(gA + (size_t)(i * 8) * Kq + k0, &As[(wave * 32 + i * 8) * 64]);
      glds16(gB + (size_t)(i * 8) * Kq + k0, &Bs[(wave * 32 + i * 8) * 64]);
    }
    __syncthreads();
#pragma unroll
    for (int kk = 0; kk < 64; kk += 32) {
      short8 af[4], bfr[4];
#pragma unroll
      for (int t = 0; t < 4; t++) {
        int row = wm * 64 + t * 16 + l16;
        int cb = (kk >> 3) + ql;
        af[t] = *(const short8*)&As[row * 64 + ((cb ^ (row & 7)) << 3)];
      }
#pragma unroll
      for (int t = 0; t < 4; t++) {
        int row = wn * 64 + t * 16 + l16;
        int cb = (kk >> 3) + ql;
        bfr[t] = *(const short8*)&Bs[row * 64 + ((cb ^ (row & 7)) << 3)];
      }
#pragma unroll
      for (int i = 0; i < 4; i++)
#pragma unroll
        for (int j = 0; j < 4; j++) acc[i][j] = mfma16(af[i], bfr[j], acc[i][j]);
    }
  }
#pragma unroll
  for (int i = 0; i < 4; i++)
#pragma unroll
    for (int j = 0; j < 4; j++)
#pragma unroll
      for (int r = 0; r < 4; r++) {
        int rr = row0 + wm * 64 + i * 16 + ql * 4 + r;
        int cc = c0l + wn * 64 + j * 16 + l16;
        dst[(size_t)rr * DIc + cc] = f2bf(acc[i][j][r]);
      }
}

// ---------------- C[M][N] = A[M][K] * BT[N][K]^T (final GEMM, fp32 out) ----------------
__global__ __launch_bounds__(256) void gemm_glds(const unsigned short* __restrict__ A,
                                                 const unsigned short* __restrict__ BT,
                                                 float* __restrict__ Cout,
                                                 int Mq, int Nq, int Kq) {
  __shared__ unsigned short As[128 * 64];
  __shared__ unsigned short Bs[128 * 64];
  int row0 = blockIdx.x * 128, col0 = blockIdx.y * 128;
  int tid = threadIdx.x, lane = tid & 63, wave = tid >> 6;
  int wm = wave >> 1, wn = wave & 1;
  int ql = lane >> 4, l16 = lane & 15;
  int r8 = lane >> 3, cbl = (lane & 7) ^ r8;

  const unsigned short* gA = A + (size_t)(row0 + wave * 32 + r8) * Kq + cbl * 8;
  const unsigned short* gB = BT + (size_t)(col0 + wave * 32 + r8) * Kq + cbl * 8;

  f32x4 acc[4][4];
#pragma unroll
  for (int i = 0; i < 4; i++)
#pragma unroll
    for (int j = 0; j < 4; j++) acc[i][j] = (f32x4){0.f, 0.f, 0.f, 0.f};

  for (int k0 = 0; k0 < Kq; k0 += 64) {
    __syncthreads();
#pragma unroll
    for (int i = 0; i < 4; ++i) {
      glds16(gA + (size_t)(i * 8) * Kq + k0, &As[(wave * 32 + i * 8) * 64]);
      glds16(gB + (size_t)(i * 8) * Kq + k0, &Bs[(wave * 32 + i * 8) * 64]);
    }
    __syncthreads();
#pragma unroll
    for (int kk = 0; kk < 64; kk += 32) {
      short8 af[4], bfr[4];
#pragma unroll
      for (int t = 0; t < 4; t++) {
        int row = wm * 64 + t * 16 + l16;
        int cb = (kk >> 3) + ql;
        af[t] = *(const short8*)&As[row * 64 + ((cb ^ (row & 7)) << 3)];
      }
#pragma unroll
      for (int t = 0; t < 4; t++) {
        int row = wn * 64 + t * 16 + l16;
        int cb = (kk >> 3) + ql;
        bfr[t] = *(const short8*)&Bs[row * 64 + ((cb ^ (row & 7)) << 3)];
      }
#pragma unroll
      for (int i = 0; i < 4; i++)
#pragma unroll
        for (int j = 0; j < 4; j++) acc[i][j] = mfma16(af[i], bfr[j], acc[i][j]);
    }
  }
#pragma unroll
  for (int i = 0; i < 4; i++)
#pragma unroll
    for (int j = 0; j < 4; j++)
#pragma unroll
      for (int r = 0; r < 4; r++) {
        int rr = row0 + wm * 64 + i * 16 + ql * 4 + r;
        int cc = col0 + wn * 64 + j * 16 + l16;
        Cout[(size_t)rr * Nq + cc] = acc[i][j][r];
      }
}

// ---------------- per-head normalize -> fp16 (Q/K now UNPADDED 16 dims) ----------------
__global__ __launch_bounds__(256) void norm_kernel(const unsigned short* __restrict__ QG,
                                                   const unsigned short* __restrict__ KV,
                                                   unsigned short* __restrict__ Qn,   // fp16 [bh][n][16]
                                                   unsigned short* __restrict__ Kn,   // fp16 [bh][n][16]
                                                   unsigned short* __restrict__ Vtg)  // fp16 [bh][d][n]
{
  int g = blockIdx.x * 256 + threadIdx.x;
  int n = g & (Nc - 1), bh = g >> 11;
  int h = bh & 15, b = bh >> 4;
  size_t src = ((size_t)(b * Nc + n)) * DIc + h * 80;

  {
    ushort8 u0 = *(const ushort8*)&QG[src];
    ushort8 u1 = *(const ushort8*)&QG[src + 8];
    float q[16], ss = 0.f;
#pragma unroll
    for (int i = 0; i < 8; i++) { q[i] = bf2f(u0[i]); q[8 + i] = bf2f(u1[i]); }
#pragma unroll
    for (int i = 0; i < 16; i++) ss += q[i] * q[i];
    float sc = 1.f / fmaxf(sqrtf(ss), 1e-12f);
    half8 o0, o1;
#pragma unroll
    for (int i = 0; i < 8; i++) { o0[i] = (_Float16)(q[i] * sc); o1[i] = (_Float16)(q[8 + i] * sc); }
    size_t dst = ((size_t)bh * Nc + n) * 16;
    *(half8*)&Qn[dst] = o0;
    *(half8*)&Qn[dst + 8] = o1;
  }
  {
    ushort8 u0 = *(const ushort8*)&KV[src];
    ushort8 u1 = *(const ushort8*)&KV[src + 8];
    float q[16], ss = 0.f;
#pragma unroll
    for (int i = 0; i < 8; i++) { q[i] = bf2f(u0[i]); q[8 + i] = bf2f(u1[i]); }
#pragma unroll
    for (int i = 0; i < 16; i++) ss += q[i] * q[i];
    float sc = 1.f / fmaxf(sqrtf(ss), 1e-12f);
    half8 o0, o1;
#pragma unroll
    for (int i = 0; i < 8; i++) { o0[i] = (_Float16)(q[i] * sc); o1[i] = (_Float16)(q[8 + i] * sc); }
    size_t dst = ((size_t)bh * Nc + n) * 16;
    *(half8*)&Kn[dst] = o0;
    *(half8*)&Kn[dst + 8] = o1;
  }
  {
    ushort8 u[8];
#pragma unroll
    for (int i = 0; i < 8; i++) u[i] = *(const ushort8*)&KV[src + 16 + i * 8];
    float ss = 0.f;
#pragma unroll
    for (int i = 0; i < 8; i++)
#pragma unroll
      for (int j = 0; j < 8; j++) { float x = bf2f(u[i][j]); ss += x * x; }
    float sc = 1.f / fmaxf(sqrtf(ss), 1e-12f);
#pragma unroll
    for (int i = 0; i < 8; i++)
#pragma unroll
      for (int j = 0; j < 8; j++) {
        int d = i * 8 + j;
        union { _Float16 h; unsigned short us; } cv;
        cv.h = (_Float16)(bf2f(u[i][j]) * sc);
        Vtg[((size_t)bh * DVc + d) * Nc + n] = cv.us;
      }
  }
}

// ---------------- relu^2 attention, fp16 datapath ----------------
// R7: (a) V reg-staged with parity-mixing swizzle pi_r(g) = g ^ (r&15) on 8B
// granules -> both ds_write_b128 and the 2x ds_read_b64 PV reads hit the bank
// minimum (glds16's 16B placement granularity forced bit0 of the read granule
// to ql&1 -> 2-way conflict on EVERY read, SQ_LDS_BANK_CONFLICT = 2^23).
// (b) S-MFMA K=16 (exact, unpadded) via mfma_f32_16x16x16f16.
// (c) kf register double-buffer: next tile's K-frags issued at tile top.
// (d) s_setprio(1) around the PV MFMA cluster (T5, m191 regime).
__global__ __launch_bounds__(256, 4) void attn_kernel(const unsigned short* __restrict__ Qn,
                                                      const unsigned short* __restrict__ Kn,
                                                      const unsigned short* __restrict__ Vtg,
                                                      const unsigned short* __restrict__ QG,
                                                      unsigned short* __restrict__ outpre) {
  __shared__ unsigned short shm[2 * 64 * 128];  // vt[2][64][128] fp16 (32KB); epilogue aliases of[128][68]

  int gid = blockIdx.x;
  int xcd = gid & 7, slot = gid >> 3;
  int bh = xcd * 8 + (slot & 7);
  int q0 = (slot >> 3) * 128;
  int b = bh >> 4, h = bh & 15;
  int tid = threadIdx.x, lane = tid & 63, wave = tid >> 6;
  int ql = lane >> 4, l16 = lane & 15;
  int qw0 = q0 + wave * 32;

  // Q fragments (B-operand of S-mfma, K=16), resident: q = qw0 + qt*16 + l16
  half4 qf[2];
#pragma unroll
  for (int qt = 0; qt < 2; ++qt)
    qf[qt] = *(const half4*)&Qn[((size_t)bh * Nc + qw0 + qt * 16 + l16) * 16 + ql * 4];

  const unsigned short* krow = Kn + (size_t)bh * Nc * 16;
  const unsigned short* vbase = Vtg + ((size_t)bh * DVc) * Nc;

  // V staging role: for j in 0..3, lane handles row r = wave*16 + 4j + (lane>>4),
  // 16B source granule m = lane&15 (fully coalesced 256B/row).
  int lq = lane >> 4, m16 = lane & 15;
  unsigned swp = (unsigned)(lq & 1);  // row parity -> swap 8B halves at store

  f32x4 acc[4][2];
#pragma unroll
  for (int dt = 0; dt < 4; dt++) { acc[dt][0] = (f32x4){0.f,0.f,0.f,0.f}; acc[dt][1] = (f32x4){0.f,0.f,0.f,0.f}; }

  half4 kfA[8], kfB[8];
  uint4 vg[4];

  // ---- prologue: kf tile 0 -> kfA; V tile 0 -> buf0 (swizzled reg-stage) ----
#pragma unroll
  for (int kh = 0; kh < 8; ++kh)
    kfA[kh] = *(const half4*)&krow[(size_t)(kh * 16 + l16) * 16 + ql * 4];
#pragma unroll
  for (int j = 0; j < 4; ++j) {
    int r = wave * 16 + 4 * j + lq;
    vg[j] = *(const uint4*)&vbase[(size_t)r * Nc + m16 * 8];
  }
#pragma unroll
  for (int j = 0; j < 4; ++j) {
    int r = wave * 16 + 4 * j + lq;
    int M = m16 ^ ((r & 15) >> 1);
    uint4 t = vg[j], o;
    o.x = swp ? t.z : t.x; o.y = swp ? t.w : t.y;
    o.z = swp ? t.x : t.z; o.w = swp ? t.y : t.w;
    *(uint4*)&shm[r * 128 + M * 8] = o;
  }

#define TILE_BODY(KT, KFU, KFN, LN)                                                      \
  {                                                                                      \
    __syncthreads(); /* publishes ds_writes + kf/V issued last tile */                   \
    unsigned short* vtb = &shm[((KT) & 1) * 8192];                                       \
    unsigned short* vnb = &shm[(((KT) + 1) & 1) * 8192];                                 \
    if (LN) {                                                                            \
      int kn0 = ((KT) + 1) * 128;                                                        \
      _Pragma("unroll") for (int kh = 0; kh < 8; ++kh)                                   \
        KFN[kh] = *(const half4*)&krow[(size_t)(kn0 + kh * 16 + l16) * 16 + ql * 4];     \
      _Pragma("unroll") for (int j = 0; j < 4; ++j) {                                    \
        int r = wave * 16 + 4 * j + lq;                                                  \
        vg[j] = *(const uint4*)&vbase[(size_t)r * Nc + kn0 + m16 * 8];                   \
      }                                                                                  \
    }                                                                                    \
    _Pragma("unroll") for (int p = 0; p < 4; ++p) { /* 32-key group */                   \
      f32x4 c0[2], c1[2];                                                                \
      _Pragma("unroll") for (int qt = 0; qt < 2; ++qt) {                                 \
        c0[qt] = mfma16k(KFU[2 * p],     qf[qt], (f32x4){0.f, 0.f, 0.f, 0.f});           \
        c1[qt] = mfma16k(KFU[2 * p + 1], qf[qt], (f32x4){0.f, 0.f, 0.f, 0.f});           \
      }                                                                                  \
      half8 pf[2];                                                                       \
      _Pragma("unroll") for (int qt = 0; qt < 2; ++qt) {                                 \
        union { half8 hh; fp16x2 p2[4]; } w;                                             \
        fp16x2 t0 = __builtin_amdgcn_cvt_pkrtz(c0[qt][0], c0[qt][1]);                    \
        fp16x2 t1 = __builtin_amdgcn_cvt_pkrtz(c0[qt][2], c0[qt][3]);                    \
        fp16x2 t2 = __builtin_amdgcn_cvt_pkrtz(c1[qt][0], c1[qt][1]);                    \
        fp16x2 t3 = __builtin_amdgcn_cvt_pkrtz(c1[qt][2], c1[qt][3]);                    \
        const fp16x2 hz = {(__fp16)0, (__fp16)0};                                        \
        t0 = __builtin_elementwise_max(t0, hz); w.p2[0] = t0 * t0;                       \
        t1 = __builtin_elementwise_max(t1, hz); w.p2[1] = t1 * t1;                       \
        t2 = __builtin_elementwise_max(t2, hz); w.p2[2] = t2 * t2;                       \
        t3 = __builtin_elementwise_max(t3, hz); w.p2[3] = t3 * t3;                       \
        pf[qt] = w.hh;                                                                   \
      }                                                                                  \
      /* PV: stored 8B granule pos = g ^ (d&15); d&15 == l16 here */                     \
      int e1 = ((p * 8 + ql) ^ l16) << 2;                                                \
      int e2 = e1 ^ 16;                                                                  \
      __builtin_amdgcn_s_setprio(1);                                                     \
      _Pragma("unroll") for (int dt = 0; dt < 4; ++dt) {                                 \
        const unsigned short* vrow = vtb + (dt * 16 + l16) * 128;                        \
        union { half8 s; uint4 u; } vf;                                                  \
        uint2 va = *(const uint2*)&vrow[e1];                                             \
        uint2 vb2 = *(const uint2*)&vrow[e2];                                            \
        vf.u.x = va.x; vf.u.y = va.y; vf.u.z = vb2.x; vf.u.w = vb2.y;                    \
        _Pragma("unroll") for (int qt = 0; qt < 2; ++qt)                                 \
          acc[dt][qt] = mfma16h(vf.s, pf[qt], acc[dt][qt]);                              \
      }                                                                                  \
      __builtin_amdgcn_s_setprio(0);                                                     \
    }                                                                                    \
    if (LN) { /* write staged V into other buffer; vmcnt on vg is implicit */            \
      _Pragma("unroll") for (int j = 0; j < 4; ++j) {                                    \
        int r = wave * 16 + 4 * j + lq;                                                  \
        int M = m16 ^ ((r & 15) >> 1);                                                   \
        uint4 t = vg[j], o;                                                              \
        o.x = swp ? t.z : t.x; o.y = swp ? t.w : t.y;                                    \
        o.z = swp ? t.x : t.z; o.w = swp ? t.y : t.w;                                    \
        *(uint4*)&vnb[r * 128 + M * 8] = o;                                              \
      }                                                                                  \
    }                                                                                    \
  }

#pragma unroll 1
  for (int kt2 = 0; kt2 < 8; ++kt2) {
    int kte = kt2 * 2;
    TILE_BODY(kte, kfA, kfB, 1)
    TILE_BODY(kte + 1, kfB, kfA, (kt2 < 7))
  }
#undef TILE_BODY

  __syncthreads();  // all waves done with vt before 'of' aliases shm
  unsigned short(*of)[68] = (unsigned short(*)[68])shm;

  // epilogue: lane(ql,l16) holds O[q = qt*16+l16 (local)][d = dt*16+ql*4+r]
#pragma unroll
  for (int qt = 0; qt < 2; ++qt) {
    float ss = 0.f;
#pragma unroll
    for (int dt = 0; dt < 4; ++dt)
#pragma unroll
      for (int r = 0; r < 4; ++r) { float v = acc[dt][qt][r]; ss += v * v; }
    ss += __shfl_xor(ss, 16, 64);
    ss += __shfl_xor(ss, 32, 64);
    float nrm = sqrtf(ss);
    float sc = tanhf(nrm) / fmaxf(nrm, 1e-12f);
    int q = qw0 + qt * 16 + l16;
    size_t gbase = ((size_t)(b * Nc + q)) * DIc + h * 80 + DKc;  // gate slice of QG
#pragma unroll
    for (int dt = 0; dt < 4; ++dt) {
      uint2 gu = *(const uint2*)&QG[gbase + dt * 16 + ql * 4];
      float o[4];
#pragma unroll
      for (int r = 0; r < 4; ++r) {
        unsigned short gb = (r < 2) ? (unsigned short)(gu.x >> (16 * r))
                                    : (unsigned short)(gu.y >> (16 * (r - 2)));
        float x = bf2f(gb);
        float s = x / (1.f + __expf(-x));
        float e2 = __expf(2.f * s);
        float g = 1.f - 2.f / (e2 + 1.f);  // tanh(s)
        o[r] = acc[dt][qt][r] * sc * g;
      }
      uint2 w;
      w.x = pack2bf(o[0], o[1]);
      w.y = pack2bf(o[2], o[3]);
      *(uint2*)&of[wave * 32 + qt * 16 + l16][dt * 16 + ql * 4] = w;
    }
  }
  __syncthreads();
  {
    int row = tid >> 1, cb = (tid & 1) * 32;
    size_t obase = ((size_t)(b * Nc + q0 + row)) * (Hc * DVc) + h * DVc + cb;
#pragma unroll
    for (int i = 0; i < 4; ++i)
      *(ushort8*)&outpre[obase + i * 8] = *(const ushort8*)&of[row][cb + i * 8];
  }
}

extern "C" void kernel_launch(void* const* d_in, const int* in_sizes, int n_in,
                              void* d_out, int out_size, void* d_ws, size_t ws_size,
                              hipStream_t stream) {
  const float* X = (const float*)d_in[0];     // (4,2048,1024)
  const float* Wqg = (const float*)d_in[1];   // (1024,1280)
  const float* Wkv = (const float*)d_in[2];   // (1024,1280)
  const float* Wout = (const float*)d_in[3];  // (1024,1024)
  float* out = (float*)d_out;
  (void)in_sizes; (void)n_in; (void)out_size; (void)ws_size;

  char* ws = (char*)d_ws;
  size_t off = 0;
  auto alloc = [&](size_t bytes) {
    void* p = ws + off;
    off += (bytes + 255) & ~(size_t)255;
    return p;
  };
  unsigned short* Xbf   = (unsigned short*)alloc((size_t)Mc * Dc * 2);            // 16 MB
  unsigned short* WqgT  = (unsigned short*)alloc((size_t)DIc * Dc * 2);           // 2.5 MB (WkvT MUST follow contiguously)
  unsigned short* WkvT  = (unsigned short*)alloc((size_t)DIc * Dc * 2);
  unsigned short* WoutT = (unsigned short*)alloc((size_t)Dc * Dc * 2);            // 2 MB
  unsigned short* QG    = (unsigned short*)alloc((size_t)Mc * DIc * 2);           // 20 MB
  unsigned short* KV    = (unsigned short*)alloc((size_t)Mc * DIc * 2);           // 20 MB
  unsigned short* Qn    = (unsigned short*)alloc((size_t)Bc * Hc * Nc * 16 * 2);  // 4 MB (fp16, unpadded)
  unsigned short* Kn    = (unsigned short*)alloc((size_t)Bc * Hc * Nc * 16 * 2);  // 4 MB
  unsigned short* Vtg   = (unsigned short*)alloc((size_t)Bc * Hc * Nc * DVc * 2); // 16 MB (fp16)
  unsigned short* outpre = Xbf;  // Xbf dead after projection GEMM; same size

  convert_x<<<(Mc * Dc / 8) / 256, 256, 0, stream>>>(X, Xbf, Mc * Dc / 8);
  transpose_convert<<<dim3(Dc / 64, DIc / 64), 256, 0, stream>>>(Wqg, WqgT, Dc, DIc);
  transpose_convert<<<dim3(Dc / 64, DIc / 64), 256, 0, stream>>>(Wkv, WkvT, Dc, DIc);
  transpose_convert<<<dim3(Dc / 64, Dc / 64), 256, 0, stream>>>(Wout, WoutT, Dc, Dc);
  gemm_proj<<<dim3(Mc / 128, 2 * DIc / 128), 256, 0, stream>>>(Xbf, WqgT, QG, KV, Dc);
  norm_kernel<<<(Mc * Hc) / 256, 256, 0, stream>>>(QG, KV, Qn, Kn, Vtg);
  attn_kernel<<<1024, 256, 0, stream>>>(Qn, Kn, Vtg, QG, outpre);
  gemm_glds<<<dim3(Mc / 128, Dc / 128), 256, 0, stream>>>(outpre, WoutT, out, Mc, Dc, Dc);
}

// Round 2
// 252.673 us; speedup vs baseline: 1.0381x; 1.0345x over previous
//
#include <hip/hip_runtime.h>
#include <cstdint>
#include <cstddef>

typedef __attribute__((ext_vector_type(8))) short short8;
typedef __attribute__((ext_vector_type(8))) unsigned short ushort8;
typedef __attribute__((ext_vector_type(4))) float f32x4;
typedef __attribute__((ext_vector_type(8))) _Float16 half8;
typedef __attribute__((ext_vector_type(4))) _Float16 half4;
typedef __attribute__((ext_vector_type(2))) __fp16 fp16x2;

#define DEV static __device__ __forceinline__

DEV unsigned short f2bf(float x) {
  union { float f; unsigned u; } v; v.f = x;
  unsigned r = v.u + 0x7fffu + ((v.u >> 16) & 1u);
  return (unsigned short)(r >> 16);
}
DEV float bf2f(unsigned short u) {
  union { unsigned u; float f; } v; v.u = ((unsigned)u) << 16;
  return v.f;
}
DEV unsigned pack2bf(float lo, float hi) {
  union { float f; unsigned u; } a, b; a.f = lo; b.f = hi;
  return __builtin_amdgcn_perm(b.u + 0x8000u, a.u + 0x8000u, 0x07060302u);
}
DEV f32x4 mfma16(short8 a, short8 b, f32x4 c) {
  return __builtin_amdgcn_mfma_f32_16x16x32_bf16(a, b, c, 0, 0, 0);
}
DEV f32x4 mfma16h(half8 a, half8 b, f32x4 c) {
  return __builtin_amdgcn_mfma_f32_16x16x32_f16(a, b, c, 0, 0, 0);
}
DEV f32x4 mfma16k(half4 a, half4 b, f32x4 c) {
  return __builtin_amdgcn_mfma_f32_16x16x16f16(a, b, c, 0, 0, 0);
}

// async global->LDS, 16B per lane; LDS dst = wave-uniform base + lane*16
typedef __attribute__((address_space(1))) unsigned int g_u32;
typedef __attribute__((address_space(3))) unsigned int l_u32;
DEV void glds16(const unsigned short* g, unsigned short* l) {
  __builtin_amdgcn_global_load_lds((g_u32*)g, (l_u32*)l, 16, 0, 0);
}

constexpr int Bc = 4, Nc = 2048, Dc = 1024, Hc = 16, DKc = 16, DVc = 64, DIc = 1280;
constexpr int Mc = Bc * Nc;  // 8192

// ---------------- elementwise fp32 -> bf16 ----------------
__global__ __launch_bounds__(256) void convert_x(const float* __restrict__ X,
                                                 unsigned short* __restrict__ Xb, int total8) {
  int i = blockIdx.x * 256 + threadIdx.x;
  if (i >= total8) return;
  const float4* p = (const float4*)(X + (size_t)i * 8);
  float4 a = p[0], b = p[1];
  ushort8 o;
  o[0] = f2bf(a.x); o[1] = f2bf(a.y); o[2] = f2bf(a.z); o[3] = f2bf(a.w);
  o[4] = f2bf(b.x); o[5] = f2bf(b.y); o[6] = f2bf(b.z); o[7] = f2bf(b.w);
  *(ushort8*)(Xb + (size_t)i * 8) = o;
}

// ---------------- W[K][N] fp32 -> WT[N][K] bf16 ----------------
__global__ __launch_bounds__(256) void transpose_convert(const float* __restrict__ W,
                                                         unsigned short* __restrict__ WT,
                                                         int K, int N) {
  __shared__ unsigned short t[64][72];
  int k0 = blockIdx.x * 64, n0 = blockIdx.y * 64;
  int tid = threadIdx.x;
#pragma unroll
  for (int it = 0; it < 16; ++it) {
    int f = it * 256 + tid;
    int r = f >> 6, c = f & 63;
    t[c][r] = f2bf(W[(size_t)(k0 + r) * N + n0 + c]);
  }
  __syncthreads();
#pragma unroll
  for (int it = 0; it < 16; ++it) {
    int f = it * 256 + tid;
    int r = f >> 6, c = f & 63;
    WT[(size_t)(n0 + r) * K + k0 + c] = t[r][c];
  }
}

// ---------------- fused projection GEMM: C = Xbf * [WqgT | WkvT]^T ----------------
__global__ __launch_bounds__(256) void gemm_proj(const unsigned short* __restrict__ A,
                                                 const unsigned short* __restrict__ BT,
                                                 unsigned short* __restrict__ QG,
                                                 unsigned short* __restrict__ KV,
                                                 int Kq) {
  __shared__ unsigned short As[128 * 64];
  __shared__ unsigned short Bs[128 * 64];
  int row0 = blockIdx.x * 128, col0 = blockIdx.y * 128;
  int tid = threadIdx.x, lane = tid & 63, wave = tid >> 6;
  int wm = wave >> 1, wn = wave & 1;
  int ql = lane >> 4, l16 = lane & 15;
  int r8 = lane >> 3, cbl = (lane & 7) ^ r8;

  unsigned short* dst = (col0 >= DIc) ? KV : QG;
  int c0l = (col0 >= DIc) ? col0 - DIc : col0;

  const unsigned short* gA = A + (size_t)(row0 + wave * 32 + r8) * Kq + cbl * 8;
  const unsigned short* gB = BT + (size_t)(col0 + wave * 32 + r8) * Kq + cbl * 8;

  f32x4 acc[4][4];
#pragma unroll
  for (int i = 0; i < 4; i++)
#pragma unroll
    for (int j = 0; j < 4; j++) acc[i][j] = (f32x4){0.f, 0.f, 0.f, 0.f};

  for (int k0 = 0; k0 < Kq; k0 += 64) {
    __syncthreads();
#pragma unroll
    for (int i = 0; i < 4; ++i) {
      glds16(gA + (size_t)(i * 8) * Kq + k0, &As[(wave * 32 + i * 8) * 64]);
      glds16(gB + (size_t)(i * 8) * Kq + k0, &Bs[(wave * 32 + i * 8) * 64]);
    }
    __syncthreads();
#pragma unroll
    for (int kk = 0; kk < 64; kk += 32) {
      short8 af[4], bfr[4];
#pragma unroll
      for (int t = 0; t < 4; t++) {
        int row = wm * 64 + t * 16 + l16;
        int cb = (kk >> 3) + ql;
        af[t] = *(const short8*)&As[row * 64 + ((cb ^ (row & 7)) << 3)];
      }
#pragma unroll
      for (int t = 0; t < 4; t++) {
        int row = wn * 64 + t * 16 + l16;
        int cb = (kk >> 3) + ql;
        bfr[t] = *(const short8*)&Bs[row * 64 + ((cb ^ (row & 7)) << 3)];
      }
#pragma unroll
      for (int i = 0; i < 4; i++)
#pragma unroll
        for (int j = 0; j < 4; j++) acc[i][j] = mfma16(af[i], bfr[j], acc[i][j]);
    }
  }
#pragma unroll
  for (int i = 0; i < 4; i++)
#pragma unroll
    for (int j = 0; j < 4; j++)
#pragma unroll
      for (int r = 0; r < 4; r++) {
        int rr = row0 + wm * 64 + i * 16 + ql * 4 + r;
        int cc = c0l + wn * 64 + j * 16 + l16;
        dst[(size_t)rr * DIc + cc] = f2bf(acc[i][j][r]);
      }
}

// ---------------- C[M][N] = A[M][K] * BT[N][K]^T (final GEMM, fp32 out) ----------------
__global__ __launch_bounds__(256) void gemm_glds(const unsigned short* __restrict__ A,
                                                 const unsigned short* __restrict__ BT,
                                                 float* __restrict__ Cout,
                                                 int Mq, int Nq, int Kq) {
  __shared__ unsigned short As[128 * 64];
  __shared__ unsigned short Bs[128 * 64];
  int row0 = blockIdx.x * 128, col0 = blockIdx.y * 128;
  int tid = threadIdx.x, lane = tid & 63, wave = tid >> 6;
  int wm = wave >> 1, wn = wave & 1;
  int ql = lane >> 4, l16 = lane & 15;
  int r8 = lane >> 3, cbl = (lane & 7) ^ r8;

  const unsigned short* gA = A + (size_t)(row0 + wave * 32 + r8) * Kq + cbl * 8;
  const unsigned short* gB = BT + (size_t)(col0 + wave * 32 + r8) * Kq + cbl * 8;

  f32x4 acc[4][4];
#pragma unroll
  for (int i = 0; i < 4; i++)
#pragma unroll
    for (int j = 0; j < 4; j++) acc[i][j] = (f32x4){0.f, 0.f, 0.f, 0.f};

  for (int k0 = 0; k0 < Kq; k0 += 64) {
    __syncthreads();
#pragma unroll
    for (int i = 0; i < 4; ++i) {
      glds16(gA + (size_t)(i * 8) * Kq + k0, &As[(wave * 32 + i * 8) * 64]);
      glds16(gB + (size_t)(i * 8) * Kq + k0, &Bs[(wave * 32 + i * 8) * 64]);
    }
    __syncthreads();
#pragma unroll
    for (int kk = 0; kk < 64; kk += 32) {
      short8 af[4], bfr[4];
#pragma unroll
      for (int t = 0; t < 4; t++) {
        int row = wm * 64 + t * 16 + l16;
        int cb = (kk >> 3) + ql;
        af[t] = *(const short8*)&As[row * 64 + ((cb ^ (row & 7)) << 3)];
      }
#pragma unroll
      for (int t = 0; t < 4; t++) {
        int row = wn * 64 + t * 16 + l16;
        int cb = (kk >> 3) + ql;
        bfr[t] = *(const short8*)&Bs[row * 64 + ((cb ^ (row & 7)) << 3)];
      }
#pragma unroll
      for (int i = 0; i < 4; i++)
#pragma unroll
        for (int j = 0; j < 4; j++) acc[i][j] = mfma16(af[i], bfr[j], acc[i][j]);
    }
  }
#pragma unroll
  for (int i = 0; i < 4; i++)
#pragma unroll
    for (int j = 0; j < 4; j++)
#pragma unroll
      for (int r = 0; r < 4; r++) {
        int rr = row0 + wm * 64 + i * 16 + ql * 4 + r;
        int cc = col0 + wn * 64 + j * 16 + l16;
        Cout[(size_t)rr * Nq + cc] = acc[i][j][r];
      }
}

// ---------------- per-head normalize -> fp16 (Q/K unpadded 16 dims) ----------------
__global__ __launch_bounds__(256) void norm_kernel(const unsigned short* __restrict__ QG,
                                                   const unsigned short* __restrict__ KV,
                                                   unsigned short* __restrict__ Qn,   // fp16 [bh][n][16]
                                                   unsigned short* __restrict__ Kn,   // fp16 [bh][n][16]
                                                   unsigned short* __restrict__ Vtg)  // fp16 [bh][d][n]
{
  int g = blockIdx.x * 256 + threadIdx.x;
  int n = g & (Nc - 1), bh = g >> 11;
  int h = bh & 15, b = bh >> 4;
  size_t src = ((size_t)(b * Nc + n)) * DIc + h * 80;

  {
    ushort8 u0 = *(const ushort8*)&QG[src];
    ushort8 u1 = *(const ushort8*)&QG[src + 8];
    float q[16], ss = 0.f;
#pragma unroll
    for (int i = 0; i < 8; i++) { q[i] = bf2f(u0[i]); q[8 + i] = bf2f(u1[i]); }
#pragma unroll
    for (int i = 0; i < 16; i++) ss += q[i] * q[i];
    float sc = 1.f / fmaxf(sqrtf(ss), 1e-12f);
    half8 o0, o1;
#pragma unroll
    for (int i = 0; i < 8; i++) { o0[i] = (_Float16)(q[i] * sc); o1[i] = (_Float16)(q[8 + i] * sc); }
    size_t dst = ((size_t)bh * Nc + n) * 16;
    *(half8*)&Qn[dst] = o0;
    *(half8*)&Qn[dst + 8] = o1;
  }
  {
    ushort8 u0 = *(const ushort8*)&KV[src];
    ushort8 u1 = *(const ushort8*)&KV[src + 8];
    float q[16], ss = 0.f;
#pragma unroll
    for (int i = 0; i < 8; i++) { q[i] = bf2f(u0[i]); q[8 + i] = bf2f(u1[i]); }
#pragma unroll
    for (int i = 0; i < 16; i++) ss += q[i] * q[i];
    float sc = 1.f / fmaxf(sqrtf(ss), 1e-12f);
    half8 o0, o1;
#pragma unroll
    for (int i = 0; i < 8; i++) { o0[i] = (_Float16)(q[i] * sc); o1[i] = (_Float16)(q[8 + i] * sc); }
    size_t dst = ((size_t)bh * Nc + n) * 16;
    *(half8*)&Kn[dst] = o0;
    *(half8*)&Kn[dst + 8] = o1;
  }
  {
    ushort8 u[8];
#pragma unroll
    for (int i = 0; i < 8; i++) u[i] = *(const ushort8*)&KV[src + 16 + i * 8];
    float ss = 0.f;
#pragma unroll
    for (int i = 0; i < 8; i++)
#pragma unroll
      for (int j = 0; j < 8; j++) { float x = bf2f(u[i][j]); ss += x * x; }
    float sc = 1.f / fmaxf(sqrtf(ss), 1e-12f);
#pragma unroll
    for (int i = 0; i < 8; i++)
#pragma unroll
      for (int j = 0; j < 8; j++) {
        int d = i * 8 + j;
        union { _Float16 h; unsigned short us; } cv;
        cv.h = (_Float16)(bf2f(u[i][j]) * sc);
        Vtg[((size_t)bh * DVc + d) * Nc + n] = cv.us;
      }
  }
}

// ---------------- relu^2 attention, fp16 datapath ----------------
// R8 post-mortem of R7: reg-staged V (swizzled ds_write) zeroed
// SQ_LDS_BANK_CONFLICT but REGRESSED 74->81us: the 2-way read conflict it
// removed is ~free (m136: 1.02x), while reg-staging added ~40 VALU/tile +
// 4 ds_write + vmcnt stall in-wave. REVERTED to async glds16 V staging with
// per-lane-source 16B-granule swizzle (read pays benign 2-way conflict).
// KEPT from R7: (a) K=16 S-MFMA (mfma_f32_16x16x16f16, exact unpadded dims),
// (b) kf register double-buffer (kills ~250cy tile-top K-load stall),
// (c) unpadded 16-wide Qn/Kn (half the K/Q fetch), (d) setprio around PV.
__global__ __launch_bounds__(256, 4) void attn_kernel(const unsigned short* __restrict__ Qn,
                                                      const unsigned short* __restrict__ Kn,
                                                      const unsigned short* __restrict__ Vtg,
                                                      const unsigned short* __restrict__ QG,
                                                      unsigned short* __restrict__ outpre) {
  __shared__ unsigned short shm[2 * 64 * 128];  // vt[2][64][128] fp16 (32KB); epilogue aliases of[128][68]

  int gid = blockIdx.x;
  int xcd = gid & 7, slot = gid >> 3;
  int bh = xcd * 8 + (slot & 7);
  int q0 = (slot >> 3) * 128;
  int b = bh >> 4, h = bh & 15;
  int tid = threadIdx.x, lane = tid & 63, wave = tid >> 6;
  int ql = lane >> 4, l16 = lane & 15;
  int qw0 = q0 + wave * 32;

  // Q fragments (B-operand of S-mfma, K=16), resident: q = qw0 + qt*16 + l16
  half4 qf[2];
#pragma unroll
  for (int qt = 0; qt < 2; ++qt)
    qf[qt] = *(const half4*)&Qn[((size_t)bh * Nc + qw0 + qt * 16 + l16) * 16 + ql * 4];

  const unsigned short* krow = Kn + (size_t)bh * Nc * 16;
  const unsigned short* vbase = Vtg + ((size_t)bh * DVc) * Nc;

  int lq = lane >> 4, m16 = lane & 15;

  f32x4 acc[4][2];
#pragma unroll
  for (int dt = 0; dt < 4; dt++) { acc[dt][0] = (f32x4){0.f,0.f,0.f,0.f}; acc[dt][1] = (f32x4){0.f,0.f,0.f,0.f}; }

  half4 kfA[8], kfB[8];

  // ---- prologue: kf tile 0 -> kfA; V tile 0 -> buf0 via async glds16 ----
#pragma unroll
  for (int kh = 0; kh < 8; ++kh)
    kfA[kh] = *(const half4*)&krow[(size_t)(kh * 16 + l16) * 16 + ql * 4];
#pragma unroll
  for (int i = 0; i < 4; ++i) {
    int r0 = i * 16 + wave * 4;
    int d = r0 + lq;
    glds16(vbase + (size_t)d * Nc + 0 + ((m16 ^ (d & 7)) << 3), &shm[r0 * 128]);
  }

#define TILE_BODY(KT, KFU, KFN, LN)                                                      \
  {                                                                                      \
    __syncthreads(); /* drains glds for this tile; all waves done reading prev buf */    \
    unsigned short* vtb = &shm[((KT) & 1) * 8192];                                       \
    if (LN) {                                                                            \
      int kn0 = ((KT) + 1) * 128;                                                        \
      unsigned short* nb = &shm[(((KT) + 1) & 1) * 8192];                                \
      _Pragma("unroll") for (int i = 0; i < 4; ++i) {                                    \
        int r0 = i * 16 + wave * 4;                                                      \
        int d = r0 + lq;                                                                 \
        glds16(vbase + (size_t)d * Nc + kn0 + ((m16 ^ (d & 7)) << 3), &nb[r0 * 128]);    \
      }                                                                                  \
      _Pragma("unroll") for (int kh = 0; kh < 8; ++kh)                                   \
        KFN[kh] = *(const half4*)&krow[(size_t)(kn0 + kh * 16 + l16) * 16 + ql * 4];     \
    }                                                                                    \
    _Pragma("unroll") for (int p = 0; p < 4; ++p) { /* 32-key group */                   \
      f32x4 c0[2], c1[2];                                                                \
      _Pragma("unroll") for (int qt = 0; qt < 2; ++qt) {                                 \
        c0[qt] = mfma16k(KFU[2 * p],     qf[qt], (f32x4){0.f, 0.f, 0.f, 0.f});           \
        c1[qt] = mfma16k(KFU[2 * p + 1], qf[qt], (f32x4){0.f, 0.f, 0.f, 0.f});           \
      }                                                                                  \
      half8 pf[2];                                                                       \
      _Pragma("unroll") for (int qt = 0; qt < 2; ++qt) {                                 \
        union { half8 hh; fp16x2 p2[4]; } w;                                             \
        fp16x2 t0 = __builtin_amdgcn_cvt_pkrtz(c0[qt][0], c0[qt][1]);                    \
        fp16x2 t1 = __builtin_amdgcn_cvt_pkrtz(c0[qt][2], c0[qt][3]);                    \
        fp16x2 t2 = __builtin_amdgcn_cvt_pkrtz(c1[qt][0], c1[qt][1]);                    \
        fp16x2 t3 = __builtin_amdgcn_cvt_pkrtz(c1[qt][2], c1[qt][3]);                    \
        const fp16x2 hz = {(__fp16)0, (__fp16)0};                                        \
        t0 = __builtin_elementwise_max(t0, hz); w.p2[0] = t0 * t0;                       \
        t1 = __builtin_elementwise_max(t1, hz); w.p2[1] = t1 * t1;                       \
        t2 = __builtin_elementwise_max(t2, hz); w.p2[2] = t2 * t2;                       \
        t3 = __builtin_elementwise_max(t3, hz); w.p2[3] = t3 * t3;                       \
        pf[qt] = w.hh;                                                                   \
      }                                                                                  \
      /* PV: A = V^T frags from LDS (16B-granule swizzle, permuted key order) */         \
      int tsw = (l16 & 7) << 1;                                                          \
      int s1 = ((p * 8 + ql) ^ tsw) << 2;                                                \
      int s2 = ((p * 8 + 4 + ql) ^ tsw) << 2;                                            \
      __builtin_amdgcn_s_setprio(1);                                                     \
      _Pragma("unroll") for (int dt = 0; dt < 4; ++dt) {                                 \
        const unsigned short* vrow = vtb + (dt * 16 + l16) * 128;                        \
        union { half8 s; uint4 u; } vf;                                                  \
        uint2 va = *(const uint2*)&vrow[s1];                                             \
        uint2 vb2 = *(const uint2*)&vrow[s2];                                            \
        vf.u.x = va.x; vf.u.y = va.y; vf.u.z = vb2.x; vf.u.w = vb2.y;                    \
        _Pragma("unroll") for (int qt = 0; qt < 2; ++qt)                                 \
          acc[dt][qt] = mfma16h(vf.s, pf[qt], acc[dt][qt]);                              \
      }                                                                                  \
      __builtin_amdgcn_s_setprio(0);                                                     \
    }                                                                                    \
  }

#pragma unroll 1
  for (int kt2 = 0; kt2 < 8; ++kt2) {
    int kte = kt2 * 2;
    TILE_BODY(kte, kfA, kfB, 1)
    TILE_BODY(kte + 1, kfB, kfA, (kt2 < 7))
  }
#undef TILE_BODY

  __syncthreads();  // all waves done with vt before 'of' aliases shm
  unsigned short(*of)[68] = (unsigned short(*)[68])shm;

  // epilogue: lane(ql,l16) holds O[q = qt*16+l16 (local)][d = dt*16+ql*4+r]
#pragma unroll
  for (int qt = 0; qt < 2; ++qt) {
    float ss = 0.f;
#pragma unroll
    for (int dt = 0; dt < 4; ++dt)
#pragma unroll
      for (int r = 0; r < 4; ++r) { float v = acc[dt][qt][r]; ss += v * v; }
    ss += __shfl_xor(ss, 16, 64);
    ss += __shfl_xor(ss, 32, 64);
    float nrm = sqrtf(ss);
    float sc = tanhf(nrm) / fmaxf(nrm, 1e-12f);
    int q = qw0 + qt * 16 + l16;
    size_t gbase = ((size_t)(b * Nc + q)) * DIc + h * 80 + DKc;  // gate slice of QG
#pragma unroll
    for (int dt = 0; dt < 4; ++dt) {
      uint2 gu = *(const uint2*)&QG[gbase + dt * 16 + ql * 4];
      float o[4];
#pragma unroll
      for (int r = 0; r < 4; ++r) {
        unsigned short gb = (r < 2) ? (unsigned short)(gu.x >> (16 * r))
                                    : (unsigned short)(gu.y >> (16 * (r - 2)));
        float x = bf2f(gb);
        float s = x / (1.f + __expf(-x));
        float e2 = __expf(2.f * s);
        float g = 1.f - 2.f / (e2 + 1.f);  // tanh(s)
        o[r] = acc[dt][qt][r] * sc * g;
      }
      uint2 w;
      w.x = pack2bf(o[0], o[1]);
      w.y = pack2bf(o[2], o[3]);
      *(uint2*)&of[wave * 32 + qt * 16 + l16][dt * 16 + ql * 4] = w;
    }
  }
  __syncthreads();
  {
    int row = tid >> 1, cb = (tid & 1) * 32;
    size_t obase = ((size_t)(b * Nc + q0 + row)) * (Hc * DVc) + h * DVc + cb;
#pragma unroll
    for (int i = 0; i < 4; ++i)
      *(ushort8*)&outpre[obase + i * 8] = *(const ushort8*)&of[row][cb + i * 8];
  }
}

extern "C" void kernel_launch(void* const* d_in, const int* in_sizes, int n_in,
                              void* d_out, int out_size, void* d_ws, size_t ws_size,
                              hipStream_t stream) {
  const float* X = (const float*)d_in[0];     // (4,2048,1024)
  const float* Wqg = (const float*)d_in[1];   // (1024,1280)
  const float* Wkv = (const float*)d_in[2];   // (1024,1280)
  const float* Wout = (const float*)d_in[3];  // (1024,1024)
  float* out = (float*)d_out;
  (void)in_sizes; (void)n_in; (void)out_size; (void)ws_size;

  char* ws = (char*)d_ws;
  size_t off = 0;
  auto alloc = [&](size_t bytes) {
    void* p = ws + off;
    off += (bytes + 255) & ~(size_t)255;
    return p;
  };
  unsigned short* Xbf   = (unsigned short*)alloc((size_t)Mc * Dc * 2);            // 16 MB
  unsigned short* WqgT  = (unsigned short*)alloc((size_t)DIc * Dc * 2);           // 2.5 MB (WkvT MUST follow contiguously)
  unsigned short* WkvT  = (unsigned short*)alloc((size_t)DIc * Dc * 2);
  unsigned short* WoutT = (unsigned short*)alloc((size_t)Dc * Dc * 2);            // 2 MB
  unsigned short* QG    = (unsigned short*)alloc((size_t)Mc * DIc * 2);           // 20 MB
  unsigned short* KV    = (unsigned short*)alloc((size_t)Mc * DIc * 2);           // 20 MB
  unsigned short* Qn    = (unsigned short*)alloc((size_t)Bc * Hc * Nc * 16 * 2);  // 4 MB (fp16, unpadded)
  unsigned short* Kn    = (unsigned short*)alloc((size_t)Bc * Hc * Nc * 16 * 2);  // 4 MB
  unsigned short* Vtg   = (unsigned short*)alloc((size_t)Bc * Hc * Nc * DVc * 2); // 16 MB (fp16)
  unsigned short* outpre = Xbf;  // Xbf dead after projection GEMM; same size

  convert_x<<<(Mc * Dc / 8) / 256, 256, 0, stream>>>(X, Xbf, Mc * Dc / 8);
  transpose_convert<<<dim3(Dc / 64, DIc / 64), 256, 0, stream>>>(Wqg, WqgT, Dc, DIc);
  transpose_convert<<<dim3(Dc / 64, DIc / 64), 256, 0, stream>>>(Wkv, WkvT, Dc, DIc);
  transpose_convert<<<dim3(Dc / 64, Dc / 64), 256, 0, stream>>>(Wout, WoutT, Dc, Dc);
  gemm_proj<<<dim3(Mc / 128, 2 * DIc / 128), 256, 0, stream>>>(Xbf, WqgT, QG, KV, Dc);
  norm_kernel<<<(Mc * Hc) / 256, 256, 0, stream>>>(QG, KV, Qn, Kn, Vtg);
  attn_kernel<<<1024, 256, 0, stream>>>(Qn, Kn, Vtg, QG, outpre);
  gemm_glds<<<dim3(Mc / 128, Dc / 128), 256, 0, stream>>>(outpre, WoutT, out, Mc, Dc, Dc);
}

// Round 3
// 244.367 us; speedup vs baseline: 1.0734x; 1.0340x over previous
//
#include <hip/hip_runtime.h>
#include <cstdint>
#include <cstddef>

typedef __attribute__((ext_vector_type(8))) short short8;
typedef __attribute__((ext_vector_type(8))) unsigned short ushort8;
typedef __attribute__((ext_vector_type(4))) float f32x4;
typedef __attribute__((ext_vector_type(8))) _Float16 half8;
typedef __attribute__((ext_vector_type(4))) _Float16 half4;
typedef __attribute__((ext_vector_type(2))) __fp16 fp16x2;

#define DEV static __device__ __forceinline__

DEV unsigned short f2bf(float x) {
  union { float f; unsigned u; } v; v.f = x;
  unsigned r = v.u + 0x7fffu + ((v.u >> 16) & 1u);
  return (unsigned short)(r >> 16);
}
DEV float bf2f(unsigned short u) {
  union { unsigned u; float f; } v; v.u = ((unsigned)u) << 16;
  return v.f;
}
DEV unsigned pack2bf(float lo, float hi) {
  union { float f; unsigned u; } a, b; a.f = lo; b.f = hi;
  return __builtin_amdgcn_perm(b.u + 0x8000u, a.u + 0x8000u, 0x07060302u);
}
DEV f32x4 mfma16(short8 a, short8 b, f32x4 c) {
  return __builtin_amdgcn_mfma_f32_16x16x32_bf16(a, b, c, 0, 0, 0);
}
DEV f32x4 mfma16h(half8 a, half8 b, f32x4 c) {
  return __builtin_amdgcn_mfma_f32_16x16x32_f16(a, b, c, 0, 0, 0);
}
DEV f32x4 mfma16k(half4 a, half4 b, f32x4 c) {
  return __builtin_amdgcn_mfma_f32_16x16x16f16(a, b, c, 0, 0, 0);
}

// async global->LDS, 16B per lane; LDS dst = wave-uniform base + lane*16
typedef __attribute__((address_space(1))) unsigned int g_u32;
typedef __attribute__((address_space(3))) unsigned int l_u32;
DEV void glds16(const unsigned short* g, unsigned short* l) {
  __builtin_amdgcn_global_load_lds((g_u32*)g, (l_u32*)l, 16, 0, 0);
}

constexpr int Bc = 4, Nc = 2048, Dc = 1024, Hc = 16, DKc = 16, DVc = 64, DIc = 1280;
constexpr int Mc = Bc * Nc;  // 8192

// ---------------- elementwise fp32 -> bf16 ----------------
__global__ __launch_bounds__(256) void convert_x(const float* __restrict__ X,
                                                 unsigned short* __restrict__ Xb, int total8) {
  int i = blockIdx.x * 256 + threadIdx.x;
  if (i >= total8) return;
  const float4* p = (const float4*)(X + (size_t)i * 8);
  float4 a = p[0], b = p[1];
  ushort8 o;
  o[0] = f2bf(a.x); o[1] = f2bf(a.y); o[2] = f2bf(a.z); o[3] = f2bf(a.w);
  o[4] = f2bf(b.x); o[5] = f2bf(b.y); o[6] = f2bf(b.z); o[7] = f2bf(b.w);
  *(ushort8*)(Xb + (size_t)i * 8) = o;
}

// ---------------- W[K][N] fp32 -> WT[N][K] bf16 ----------------
__global__ __launch_bounds__(256) void transpose_convert(const float* __restrict__ W,
                                                         unsigned short* __restrict__ WT,
                                                         int K, int N) {
  __shared__ unsigned short t[64][72];
  int k0 = blockIdx.x * 64, n0 = blockIdx.y * 64;
  int tid = threadIdx.x;
#pragma unroll
  for (int it = 0; it < 16; ++it) {
    int f = it * 256 + tid;
    int r = f >> 6, c = f & 63;
    t[c][r] = f2bf(W[(size_t)(k0 + r) * N + n0 + c]);
  }
  __syncthreads();
#pragma unroll
  for (int it = 0; it < 16; ++it) {
    int f = it * 256 + tid;
    int r = f >> 6, c = f & 63;
    WT[(size_t)(n0 + r) * K + k0 + c] = t[r][c];
  }
}

// ---------------- fused projection GEMM: C = Xbf * [WqgT | WkvT]^T ----------------
// R9: 1D grid + XCD-chunked block swizzle (T1, HK chiplet_transform_chunked).
// Default round-robin dispatch spreads B-panel sharers across XCDs -> each
// block streams 512KB through its 4MB L2 with no reuse (~640MB L2 fill).
// Chunked: XCD x owns an 8-row band x all 20 cols, snaked col-major: A band
// (2MB) stays L2-resident, B panels stream once -> ~7MB fill per XCD.
__global__ __launch_bounds__(256) void gemm_proj(const unsigned short* __restrict__ A,
                                                 const unsigned short* __restrict__ BT,
                                                 unsigned short* __restrict__ QG,
                                                 unsigned short* __restrict__ KV,
                                                 int Kq) {
  __shared__ unsigned short As[128 * 64];
  __shared__ unsigned short Bs[128 * 64];
  int L = blockIdx.x;                 // 0..1279; HW round-robins L%8 across XCDs
  int xcd = L & 7, idx = L >> 3;      // idx 0..159
  int brow = xcd * 8 + (idx & 7);     // 0..63  (8-row band per XCD)
  int bcol = idx >> 3;                // 0..19  (snake over cols within band)
  int row0 = brow * 128, col0 = bcol * 128;
  int tid = threadIdx.x, lane = tid & 63, wave = tid >> 6;
  int wm = wave >> 1, wn = wave & 1;
  int ql = lane >> 4, l16 = lane & 15;
  int r8 = lane >> 3, cbl = (lane & 7) ^ r8;

  unsigned short* dst = (col0 >= DIc) ? KV : QG;
  int c0l = (col0 >= DIc) ? col0 - DIc : col0;

  const unsigned short* gA = A + (size_t)(row0 + wave * 32 + r8) * Kq + cbl * 8;
  const unsigned short* gB = BT + (size_t)(col0 + wave * 32 + r8) * Kq + cbl * 8;

  f32x4 acc[4][4];
#pragma unroll
  for (int i = 0; i < 4; i++)
#pragma unroll
    for (int j = 0; j < 4; j++) acc[i][j] = (f32x4){0.f, 0.f, 0.f, 0.f};

  for (int k0 = 0; k0 < Kq; k0 += 64) {
    __syncthreads();
#pragma unroll
    for (int i = 0; i < 4; ++i) {
      glds16(gA + (size_t)(i * 8) * Kq + k0, &As[(wave * 32 + i * 8) * 64]);
      glds16(gB + (size_t)(i * 8) * Kq + k0, &Bs[(wave * 32 + i * 8) * 64]);
    }
    __syncthreads();
#pragma unroll
    for (int kk = 0; kk < 64; kk += 32) {
      short8 af[4], bfr[4];
#pragma unroll
      for (int t = 0; t < 4; t++) {
        int row = wm * 64 + t * 16 + l16;
        int cb = (kk >> 3) + ql;
        af[t] = *(const short8*)&As[row * 64 + ((cb ^ (row & 7)) << 3)];
      }
#pragma unroll
      for (int t = 0; t < 4; t++) {
        int row = wn * 64 + t * 16 + l16;
        int cb = (kk >> 3) + ql;
        bfr[t] = *(const short8*)&Bs[row * 64 + ((cb ^ (row & 7)) << 3)];
      }
#pragma unroll
      for (int i = 0; i < 4; i++)
#pragma unroll
        for (int j = 0; j < 4; j++) acc[i][j] = mfma16(af[i], bfr[j], acc[i][j]);
    }
  }
#pragma unroll
  for (int i = 0; i < 4; i++)
#pragma unroll
    for (int j = 0; j < 4; j++)
#pragma unroll
      for (int r = 0; r < 4; r++) {
        int rr = row0 + wm * 64 + i * 16 + ql * 4 + r;
        int cc = c0l + wn * 64 + j * 16 + l16;
        dst[(size_t)rr * DIc + cc] = f2bf(acc[i][j][r]);
      }
}

// ---------------- C[M][N] = A[M][K] * BT[N][K]^T (final GEMM, fp32 out) ----------------
// R9: same XCD-chunked swizzle; 8x8 chunk -> A 2MB + B 2MB fits per-XCD L2.
__global__ __launch_bounds__(256) void gemm_glds(const unsigned short* __restrict__ A,
                                                 const unsigned short* __restrict__ BT,
                                                 float* __restrict__ Cout,
                                                 int Mq, int Nq, int Kq) {
  __shared__ unsigned short As[128 * 64];
  __shared__ unsigned short Bs[128 * 64];
  int L = blockIdx.x;                 // 0..511
  int xcd = L & 7, idx = L >> 3;      // idx 0..63
  int brow = xcd * 8 + (idx & 7);     // 0..63
  int bcol = idx >> 3;                // 0..7
  int row0 = brow * 128, col0 = bcol * 128;
  int tid = threadIdx.x, lane = tid & 63, wave = tid >> 6;
  int wm = wave >> 1, wn = wave & 1;
  int ql = lane >> 4, l16 = lane & 15;
  int r8 = lane >> 3, cbl = (lane & 7) ^ r8;

  const unsigned short* gA = A + (size_t)(row0 + wave * 32 + r8) * Kq + cbl * 8;
  const unsigned short* gB = BT + (size_t)(col0 + wave * 32 + r8) * Kq + cbl * 8;

  f32x4 acc[4][4];
#pragma unroll
  for (int i = 0; i < 4; i++)
#pragma unroll
    for (int j = 0; j < 4; j++) acc[i][j] = (f32x4){0.f, 0.f, 0.f, 0.f};

  for (int k0 = 0; k0 < Kq; k0 += 64) {
    __syncthreads();
#pragma unroll
    for (int i = 0; i < 4; ++i) {
      glds16(gA + (size_t)(i * 8) * Kq + k0, &As[(wave * 32 + i * 8) * 64]);
      glds16(gB + (size_t)(i * 8) * Kq + k0, &Bs[(wave * 32 + i * 8) * 64]);
    }
    __syncthreads();
#pragma unroll
    for (int kk = 0; kk < 64; kk += 32) {
      short8 af[4], bfr[4];
#pragma unroll
      for (int t = 0; t < 4; t++) {
        int row = wm * 64 + t * 16 + l16;
        int cb = (kk >> 3) + ql;
        af[t] = *(const short8*)&As[row * 64 + ((cb ^ (row & 7)) << 3)];
      }
#pragma unroll
      for (int t = 0; t < 4; t++) {
        int row = wn * 64 + t * 16 + l16;
        int cb = (kk >> 3) + ql;
        bfr[t] = *(const short8*)&Bs[row * 64 + ((cb ^ (row & 7)) << 3)];
      }
#pragma unroll
      for (int i = 0; i < 4; i++)
#pragma unroll
        for (int j = 0; j < 4; j++) acc[i][j] = mfma16(af[i], bfr[j], acc[i][j]);
    }
  }
#pragma unroll
  for (int i = 0; i < 4; i++)
#pragma unroll
    for (int j = 0; j < 4; j++)
#pragma unroll
      for (int r = 0; r < 4; r++) {
        int rr = row0 + wm * 64 + i * 16 + ql * 4 + r;
        int cc = col0 + wn * 64 + j * 16 + l16;
        Cout[(size_t)rr * Nq + cc] = acc[i][j][r];
      }
}

// ---------------- per-head normalize -> fp16 (Q/K unpadded 16 dims) ----------------
__global__ __launch_bounds__(256) void norm_kernel(const unsigned short* __restrict__ QG,
                                                   const unsigned short* __restrict__ KV,
                                                   unsigned short* __restrict__ Qn,   // fp16 [bh][n][16]
                                                   unsigned short* __restrict__ Kn,   // fp16 [bh][n][16]
                                                   unsigned short* __restrict__ Vtg)  // fp16 [bh][d][n]
{
  int g = blockIdx.x * 256 + threadIdx.x;
  int n = g & (Nc - 1), bh = g >> 11;
  int h = bh & 15, b = bh >> 4;
  size_t src = ((size_t)(b * Nc + n)) * DIc + h * 80;

  {
    ushort8 u0 = *(const ushort8*)&QG[src];
    ushort8 u1 = *(const ushort8*)&QG[src + 8];
    float q[16], ss = 0.f;
#pragma unroll
    for (int i = 0; i < 8; i++) { q[i] = bf2f(u0[i]); q[8 + i] = bf2f(u1[i]); }
#pragma unroll
    for (int i = 0; i < 16; i++) ss += q[i] * q[i];
    float sc = 1.f / fmaxf(sqrtf(ss), 1e-12f);
    half8 o0, o1;
#pragma unroll
    for (int i = 0; i < 8; i++) { o0[i] = (_Float16)(q[i] * sc); o1[i] = (_Float16)(q[8 + i] * sc); }
    size_t dst = ((size_t)bh * Nc + n) * 16;
    *(half8*)&Qn[dst] = o0;
    *(half8*)&Qn[dst + 8] = o1;
  }
  {
    ushort8 u0 = *(const ushort8*)&KV[src];
    ushort8 u1 = *(const ushort8*)&KV[src + 8];
    float q[16], ss = 0.f;
#pragma unroll
    for (int i = 0; i < 8; i++) { q[i] = bf2f(u0[i]); q[8 + i] = bf2f(u1[i]); }
#pragma unroll
    for (int i = 0; i < 16; i++) ss += q[i] * q[i];
    float sc = 1.f / fmaxf(sqrtf(ss), 1e-12f);
    half8 o0, o1;
#pragma unroll
    for (int i = 0; i < 8; i++) { o0[i] = (_Float16)(q[i] * sc); o1[i] = (_Float16)(q[8 + i] * sc); }
    size_t dst = ((size_t)bh * Nc + n) * 16;
    *(half8*)&Kn[dst] = o0;
    *(half8*)&Kn[dst + 8] = o1;
  }
  {
    ushort8 u[8];
#pragma unroll
    for (int i = 0; i < 8; i++) u[i] = *(const ushort8*)&KV[src + 16 + i * 8];
    float ss = 0.f;
#pragma unroll
    for (int i = 0; i < 8; i++)
#pragma unroll
      for (int j = 0; j < 8; j++) { float x = bf2f(u[i][j]); ss += x * x; }
    float sc = 1.f / fmaxf(sqrtf(ss), 1e-12f);
#pragma unroll
    for (int i = 0; i < 8; i++)
#pragma unroll
      for (int j = 0; j < 8; j++) {
        int d = i * 8 + j;
        union { _Float16 h; unsigned short us; } cv;
        cv.h = (_Float16)(bf2f(u[i][j]) * sc);
        Vtg[((size_t)bh * DVc + d) * Nc + n] = cv.us;
      }
  }
}

// ---------------- relu^2 attention, fp16 datapath ----------------
// R8 structure (verified 68.1us): async glds16 V staging (benign 2-way read
// conflict), K=16 S-MFMA, kf register double-buffer, unpadded 16-wide Qn/Kn,
// setprio around PV. Unchanged in R9.
__global__ __launch_bounds__(256, 4) void attn_kernel(const unsigned short* __restrict__ Qn,
                                                      const unsigned short* __restrict__ Kn,
                                                      const unsigned short* __restrict__ Vtg,
                                                      const unsigned short* __restrict__ QG,
                                                      unsigned short* __restrict__ outpre) {
  __shared__ unsigned short shm[2 * 64 * 128];  // vt[2][64][128] fp16 (32KB); epilogue aliases of[128][68]

  int gid = blockIdx.x;
  int xcd = gid & 7, slot = gid >> 3;
  int bh = xcd * 8 + (slot & 7);
  int q0 = (slot >> 3) * 128;
  int b = bh >> 4, h = bh & 15;
  int tid = threadIdx.x, lane = tid & 63, wave = tid >> 6;
  int ql = lane >> 4, l16 = lane & 15;
  int qw0 = q0 + wave * 32;

  // Q fragments (B-operand of S-mfma, K=16), resident: q = qw0 + qt*16 + l16
  half4 qf[2];
#pragma unroll
  for (int qt = 0; qt < 2; ++qt)
    qf[qt] = *(const half4*)&Qn[((size_t)bh * Nc + qw0 + qt * 16 + l16) * 16 + ql * 4];

  const unsigned short* krow = Kn + (size_t)bh * Nc * 16;
  const unsigned short* vbase = Vtg + ((size_t)bh * DVc) * Nc;

  int lq = lane >> 4, m16 = lane & 15;

  f32x4 acc[4][2];
#pragma unroll
  for (int dt = 0; dt < 4; dt++) { acc[dt][0] = (f32x4){0.f,0.f,0.f,0.f}; acc[dt][1] = (f32x4){0.f,0.f,0.f,0.f}; }

  half4 kfA[8], kfB[8];

  // ---- prologue: kf tile 0 -> kfA; V tile 0 -> buf0 via async glds16 ----
#pragma unroll
  for (int kh = 0; kh < 8; ++kh)
    kfA[kh] = *(const half4*)&krow[(size_t)(kh * 16 + l16) * 16 + ql * 4];
#pragma unroll
  for (int i = 0; i < 4; ++i) {
    int r0 = i * 16 + wave * 4;
    int d = r0 + lq;
    glds16(vbase + (size_t)d * Nc + 0 + ((m16 ^ (d & 7)) << 3), &shm[r0 * 128]);
  }

#define TILE_BODY(KT, KFU, KFN, LN)                                                      \
  {                                                                                      \
    __syncthreads(); /* drains glds for this tile; all waves done reading prev buf */    \
    unsigned short* vtb = &shm[((KT) & 1) * 8192];                                       \
    if (LN) {                                                                            \
      int kn0 = ((KT) + 1) * 128;                                                        \
      unsigned short* nb = &shm[(((KT) + 1) & 1) * 8192];                                \
      _Pragma("unroll") for (int i = 0; i < 4; ++i) {                                    \
        int r0 = i * 16 + wave * 4;                                                      \
        int d = r0 + lq;                                                                 \
        glds16(vbase + (size_t)d * Nc + kn0 + ((m16 ^ (d & 7)) << 3), &nb[r0 * 128]);    \
      }                                                                                  \
      _Pragma("unroll") for (int kh = 0; kh < 8; ++kh)                                   \
        KFN[kh] = *(const half4*)&krow[(size_t)(kn0 + kh * 16 + l16) * 16 + ql * 4];     \
    }                                                                                    \
    _Pragma("unroll") for (int p = 0; p < 4; ++p) { /* 32-key group */                   \
      f32x4 c0[2], c1[2];                                                                \
      _Pragma("unroll") for (int qt = 0; qt < 2; ++qt) {                                 \
        c0[qt] = mfma16k(KFU[2 * p],     qf[qt], (f32x4){0.f, 0.f, 0.f, 0.f});           \
        c1[qt] = mfma16k(KFU[2 * p + 1], qf[qt], (f32x4){0.f, 0.f, 0.f, 0.f});           \
      }                                                                                  \
      half8 pf[2];                                                                       \
      _Pragma("unroll") for (int qt = 0; qt < 2; ++qt) {                                 \
        union { half8 hh; fp16x2 p2[4]; } w;                                             \
        fp16x2 t0 = __builtin_amdgcn_cvt_pkrtz(c0[qt][0], c0[qt][1]);                    \
        fp16x2 t1 = __builtin_amdgcn_cvt_pkrtz(c0[qt][2], c0[qt][3]);                    \
        fp16x2 t2 = __builtin_amdgcn_cvt_pkrtz(c1[qt][0], c1[qt][1]);                    \
        fp16x2 t3 = __builtin_amdgcn_cvt_pkrtz(c1[qt][2], c1[qt][3]);                    \
        const fp16x2 hz = {(__fp16)0, (__fp16)0};                                        \
        t0 = __builtin_elementwise_max(t0, hz); w.p2[0] = t0 * t0;                       \
        t1 = __builtin_elementwise_max(t1, hz); w.p2[1] = t1 * t1;                       \
        t2 = __builtin_elementwise_max(t2, hz); w.p2[2] = t2 * t2;                       \
        t3 = __builtin_elementwise_max(t3, hz); w.p2[3] = t3 * t3;                       \
        pf[qt] = w.hh;                                                                   \
      }                                                                                  \
      /* PV: A = V^T frags from LDS (16B-granule swizzle, permuted key order) */         \
      int tsw = (l16 & 7) << 1;                                                          \
      int s1 = ((p * 8 + ql) ^ tsw) << 2;                                                \
      int s2 = ((p * 8 + 4 + ql) ^ tsw) << 2;                                            \
      __builtin_amdgcn_s_setprio(1);                                                     \
      _Pragma("unroll") for (int dt = 0; dt < 4; ++dt) {                                 \
        const unsigned short* vrow = vtb + (dt * 16 + l16) * 128;                        \
        union { half8 s; uint4 u; } vf;                                                  \
        uint2 va = *(const uint2*)&vrow[s1];                                             \
        uint2 vb2 = *(const uint2*)&vrow[s2];                                            \
        vf.u.x = va.x; vf.u.y = va.y; vf.u.z = vb2.x; vf.u.w = vb2.y;                    \
        _Pragma("unroll") for (int qt = 0; qt < 2; ++qt)                                 \
          acc[dt][qt] = mfma16h(vf.s, pf[qt], acc[dt][qt]);                              \
      }                                                                                  \
      __builtin_amdgcn_s_setprio(0);                                                     \
    }                                                                                    \
  }

#pragma unroll 1
  for (int kt2 = 0; kt2 < 8; ++kt2) {
    int kte = kt2 * 2;
    TILE_BODY(kte, kfA, kfB, 1)
    TILE_BODY(kte + 1, kfB, kfA, (kt2 < 7))
  }
#undef TILE_BODY

  __syncthreads();  // all waves done with vt before 'of' aliases shm
  unsigned short(*of)[68] = (unsigned short(*)[68])shm;

  // epilogue: lane(ql,l16) holds O[q = qt*16+l16 (local)][d = dt*16+ql*4+r]
#pragma unroll
  for (int qt = 0; qt < 2; ++qt) {
    float ss = 0.f;
#pragma unroll
    for (int dt = 0; dt < 4; ++dt)
#pragma unroll
      for (int r = 0; r < 4; ++r) { float v = acc[dt][qt][r]; ss += v * v; }
    ss += __shfl_xor(ss, 16, 64);
    ss += __shfl_xor(ss, 32, 64);
    float nrm = sqrtf(ss);
    float sc = tanhf(nrm) / fmaxf(nrm, 1e-12f);
    int q = qw0 + qt * 16 + l16;
    size_t gbase = ((size_t)(b * Nc + q)) * DIc + h * 80 + DKc;  // gate slice of QG
#pragma unroll
    for (int dt = 0; dt < 4; ++dt) {
      uint2 gu = *(const uint2*)&QG[gbase + dt * 16 + ql * 4];
      float o[4];
#pragma unroll
      for (int r = 0; r < 4; ++r) {
        unsigned short gb = (r < 2) ? (unsigned short)(gu.x >> (16 * r))
                                    : (unsigned short)(gu.y >> (16 * (r - 2)));
        float x = bf2f(gb);
        float s = x / (1.f + __expf(-x));
        float e2 = __expf(2.f * s);
        float g = 1.f - 2.f / (e2 + 1.f);  // tanh(s)
        o[r] = acc[dt][qt][r] * sc * g;
      }
      uint2 w;
      w.x = pack2bf(o[0], o[1]);
      w.y = pack2bf(o[2], o[3]);
      *(uint2*)&of[wave * 32 + qt * 16 + l16][dt * 16 + ql * 4] = w;
    }
  }
  __syncthreads();
  {
    int row = tid >> 1, cb = (tid & 1) * 32;
    size_t obase = ((size_t)(b * Nc + q0 + row)) * (Hc * DVc) + h * DVc + cb;
#pragma unroll
    for (int i = 0; i < 4; ++i)
      *(ushort8*)&outpre[obase + i * 8] = *(const ushort8*)&of[row][cb + i * 8];
  }
}

extern "C" void kernel_launch(void* const* d_in, const int* in_sizes, int n_in,
                              void* d_out, int out_size, void* d_ws, size_t ws_size,
                              hipStream_t stream) {
  const float* X = (const float*)d_in[0];     // (4,2048,1024)
  const float* Wqg = (const float*)d_in[1];   // (1024,1280)
  const float* Wkv = (const float*)d_in[2];   // (1024,1280)
  const float* Wout = (const float*)d_in[3];  // (1024,1024)
  float* out = (float*)d_out;
  (void)in_sizes; (void)n_in; (void)out_size; (void)ws_size;

  char* ws = (char*)d_ws;
  size_t off = 0;
  auto alloc = [&](size_t bytes) {
    void* p = ws + off;
    off += (bytes + 255) & ~(size_t)255;
    return p;
  };
  unsigned short* Xbf   = (unsigned short*)alloc((size_t)Mc * Dc * 2);            // 16 MB
  unsigned short* WqgT  = (unsigned short*)alloc((size_t)DIc * Dc * 2);           // 2.5 MB (WkvT MUST follow contiguously)
  unsigned short* WkvT  = (unsigned short*)alloc((size_t)DIc * Dc * 2);
  unsigned short* WoutT = (unsigned short*)alloc((size_t)Dc * Dc * 2);            // 2 MB
  unsigned short* QG    = (unsigned short*)alloc((size_t)Mc * DIc * 2);           // 20 MB
  unsigned short* KV    = (unsigned short*)alloc((size_t)Mc * DIc * 2);           // 20 MB
  unsigned short* Qn    = (unsigned short*)alloc((size_t)Bc * Hc * Nc * 16 * 2);  // 4 MB (fp16, unpadded)
  unsigned short* Kn    = (unsigned short*)alloc((size_t)Bc * Hc * Nc * 16 * 2);  // 4 MB
  unsigned short* Vtg   = (unsigned short*)alloc((size_t)Bc * Hc * Nc * DVc * 2); // 16 MB (fp16)
  unsigned short* outpre = Xbf;  // Xbf dead after projection GEMM; same size

  convert_x<<<(Mc * Dc / 8) / 256, 256, 0, stream>>>(X, Xbf, Mc * Dc / 8);
  transpose_convert<<<dim3(Dc / 64, DIc / 64), 256, 0, stream>>>(Wqg, WqgT, Dc, DIc);
  transpose_convert<<<dim3(Dc / 64, DIc / 64), 256, 0, stream>>>(Wkv, WkvT, Dc, DIc);
  transpose_convert<<<dim3(Dc / 64, Dc / 64), 256, 0, stream>>>(Wout, WoutT, Dc, Dc);
  gemm_proj<<<Mc / 128 * (2 * DIc / 128), 256, 0, stream>>>(Xbf, WqgT, QG, KV, Dc);
  norm_kernel<<<(Mc * Hc) / 256, 256, 0, stream>>>(QG, KV, Qn, Kn, Vtg);
  attn_kernel<<<1024, 256, 0, stream>>>(Qn, Kn, Vtg, QG, outpre);
  gemm_glds<<<Mc / 128 * (Dc / 128), 256, 0, stream>>>(outpre, WoutT, out, Mc, Dc, Dc);
}

// Round 4
// 242.019 us; speedup vs baseline: 1.0838x; 1.0097x over previous
//
#include <hip/hip_runtime.h>
#include <cstdint>
#include <cstddef>

typedef __attribute__((ext_vector_type(8))) short short8;
typedef __attribute__((ext_vector_type(8))) unsigned short ushort8;
typedef __attribute__((ext_vector_type(4))) float f32x4;
typedef __attribute__((ext_vector_type(8))) _Float16 half8;
typedef __attribute__((ext_vector_type(4))) _Float16 half4;
typedef __attribute__((ext_vector_type(2))) __fp16 fp16x2;

#define DEV static __device__ __forceinline__

DEV unsigned short f2bf(float x) {
  union { float f; unsigned u; } v; v.f = x;
  unsigned r = v.u + 0x7fffu + ((v.u >> 16) & 1u);
  return (unsigned short)(r >> 16);
}
DEV unsigned pack2bf(float lo, float hi) {
  union { float f; unsigned u; } a, b; a.f = lo; b.f = hi;
  return __builtin_amdgcn_perm(b.u + 0x8000u, a.u + 0x8000u, 0x07060302u);
}
DEV f32x4 mfma16(short8 a, short8 b, f32x4 c) {
  return __builtin_amdgcn_mfma_f32_16x16x32_bf16(a, b, c, 0, 0, 0);
}
DEV f32x4 mfma16h(half8 a, half8 b, f32x4 c) {
  return __builtin_amdgcn_mfma_f32_16x16x32_f16(a, b, c, 0, 0, 0);
}
DEV f32x4 mfma16k(half4 a, half4 b, f32x4 c) {
  return __builtin_amdgcn_mfma_f32_16x16x16f16(a, b, c, 0, 0, 0);
}

// async global->LDS, 16B per lane; LDS dst = wave-uniform base + lane*16
typedef __attribute__((address_space(1))) unsigned int g_u32;
typedef __attribute__((address_space(3))) unsigned int l_u32;
DEV void glds16(const unsigned short* g, unsigned short* l) {
  __builtin_amdgcn_global_load_lds((g_u32*)g, (l_u32*)l, 16, 0, 0);
}

constexpr int Bc = 4, Nc = 2048, Dc = 1024, Hc = 16, DKc = 16, DVc = 64, DIc = 1280;
constexpr int Mc = Bc * Nc;  // 8192

// ---------------- merged prep: X->bf16 + 3 weight transposes (R10: 1 launch, was 4) ----
// blocks [0,4096): convert X; [4096,4416): Wqg^T; [4416,4736): Wkv^T; [4736,4992): Wout^T
__global__ __launch_bounds__(256) void prep_kernel(const float* __restrict__ X,
                                                   unsigned short* __restrict__ Xb,
                                                   const float* __restrict__ Wqg,
                                                   unsigned short* __restrict__ WqgT,
                                                   const float* __restrict__ Wkv,
                                                   unsigned short* __restrict__ WkvT,
                                                   const float* __restrict__ Wout,
                                                   unsigned short* __restrict__ WoutT) {
  __shared__ unsigned short tsh[64][72];
  int bid = blockIdx.x, tid = threadIdx.x;
  if (bid < 4096) {
    int i = bid * 256 + tid;
    const float4* p = (const float4*)(X + (size_t)i * 8);
    float4 a = p[0], b = p[1];
    ushort8 o;
    o[0] = f2bf(a.x); o[1] = f2bf(a.y); o[2] = f2bf(a.z); o[3] = f2bf(a.w);
    o[4] = f2bf(b.x); o[5] = f2bf(b.y); o[6] = f2bf(b.z); o[7] = f2bf(b.w);
    *(ushort8*)(Xb + (size_t)i * 8) = o;
    return;
  }
  const float* W; unsigned short* WT; int K, N, tb;
  if (bid < 4416)      { W = Wqg;  WT = WqgT;  K = Dc; N = DIc; tb = bid - 4096; }
  else if (bid < 4736) { W = Wkv;  WT = WkvT;  K = Dc; N = DIc; tb = bid - 4416; }
  else                 { W = Wout; WT = WoutT; K = Dc; N = Dc;  tb = bid - 4736; }
  int k0 = (tb & 15) * 64, n0 = (tb >> 4) * 64;
#pragma unroll
  for (int it = 0; it < 16; ++it) {
    int f = it * 256 + tid;
    int r = f >> 6, c = f & 63;
    tsh[c][r] = f2bf(W[(size_t)(k0 + r) * N + n0 + c]);
  }
  __syncthreads();
#pragma unroll
  for (int it = 0; it < 16; ++it) {
    int f = it * 256 + tid;
    int r = f >> 6, c = f & 63;
    WT[(size_t)(n0 + r) * K + k0 + c] = tsh[r][c];
  }
}

// ---------------- fused projection GEMM: C = Xbf * [WqgT | WkvT]^T ----------------
// R9: XCD-chunked block swizzle (T1). R10: QG/KV output is fp16 (v_cvt_f16_f32,
// 1 VALU/elem vs f2bf's 4; fp16 e5m10 is MORE precise than bf16 for these O(1) values).
__global__ __launch_bounds__(256) void gemm_proj(const unsigned short* __restrict__ A,
                                                 const unsigned short* __restrict__ BT,
                                                 unsigned short* __restrict__ QG,
                                                 unsigned short* __restrict__ KV,
                                                 int Kq) {
  __shared__ unsigned short As[128 * 64];
  __shared__ unsigned short Bs[128 * 64];
  int L = blockIdx.x;                 // 0..1279; HW round-robins L%8 across XCDs
  int xcd = L & 7, idx = L >> 3;      // idx 0..159
  int brow = xcd * 8 + (idx & 7);     // 0..63  (8-row band per XCD)
  int bcol = idx >> 3;                // 0..19
  int row0 = brow * 128, col0 = bcol * 128;
  int tid = threadIdx.x, lane = tid & 63, wave = tid >> 6;
  int wm = wave >> 1, wn = wave & 1;
  int ql = lane >> 4, l16 = lane & 15;
  int r8 = lane >> 3, cbl = (lane & 7) ^ r8;

  unsigned short* dst = (col0 >= DIc) ? KV : QG;
  int c0l = (col0 >= DIc) ? col0 - DIc : col0;

  const unsigned short* gA = A + (size_t)(row0 + wave * 32 + r8) * Kq + cbl * 8;
  const unsigned short* gB = BT + (size_t)(col0 + wave * 32 + r8) * Kq + cbl * 8;

  f32x4 acc[4][4];
#pragma unroll
  for (int i = 0; i < 4; i++)
#pragma unroll
    for (int j = 0; j < 4; j++) acc[i][j] = (f32x4){0.f, 0.f, 0.f, 0.f};

  for (int k0 = 0; k0 < Kq; k0 += 64) {
    __syncthreads();
#pragma unroll
    for (int i = 0; i < 4; ++i) {
      glds16(gA + (size_t)(i * 8) * Kq + k0, &As[(wave * 32 + i * 8) * 64]);
      glds16(gB + (size_t)(i * 8) * Kq + k0, &Bs[(wave * 32 + i * 8) * 64]);
    }
    __syncthreads();
#pragma unroll
    for (int kk = 0; kk < 64; kk += 32) {
      short8 af[4], bfr[4];
#pragma unroll
      for (int t = 0; t < 4; t++) {
        int row = wm * 64 + t * 16 + l16;
        int cb = (kk >> 3) + ql;
        af[t] = *(const short8*)&As[row * 64 + ((cb ^ (row & 7)) << 3)];
      }
#pragma unroll
      for (int t = 0; t < 4; t++) {
        int row = wn * 64 + t * 16 + l16;
        int cb = (kk >> 3) + ql;
        bfr[t] = *(const short8*)&Bs[row * 64 + ((cb ^ (row & 7)) << 3)];
      }
#pragma unroll
      for (int i = 0; i < 4; i++)
#pragma unroll
        for (int j = 0; j < 4; j++) acc[i][j] = mfma16(af[i], bfr[j], acc[i][j]);
    }
  }
#pragma unroll
  for (int i = 0; i < 4; i++)
#pragma unroll
    for (int j = 0; j < 4; j++)
#pragma unroll
      for (int r = 0; r < 4; r++) {
        int rr = row0 + wm * 64 + i * 16 + ql * 4 + r;
        int cc = c0l + wn * 64 + j * 16 + l16;
        union { _Float16 h; unsigned short us; } cv;
        cv.h = (_Float16)acc[i][j][r];
        dst[(size_t)rr * DIc + cc] = cv.us;
      }
}

// ---------------- C[M][N] = A[M][K] * BT[N][K]^T (final GEMM, fp32 out) ----------------
__global__ __launch_bounds__(256) void gemm_glds(const unsigned short* __restrict__ A,
                                                 const unsigned short* __restrict__ BT,
                                                 float* __restrict__ Cout,
                                                 int Mq, int Nq, int Kq) {
  __shared__ unsigned short As[128 * 64];
  __shared__ unsigned short Bs[128 * 64];
  int L = blockIdx.x;                 // 0..511
  int xcd = L & 7, idx = L >> 3;      // idx 0..63
  int brow = xcd * 8 + (idx & 7);     // 0..63
  int bcol = idx >> 3;                // 0..7
  int row0 = brow * 128, col0 = bcol * 128;
  int tid = threadIdx.x, lane = tid & 63, wave = tid >> 6;
  int wm = wave >> 1, wn = wave & 1;
  int ql = lane >> 4, l16 = lane & 15;
  int r8 = lane >> 3, cbl = (lane & 7) ^ r8;

  const unsigned short* gA = A + (size_t)(row0 + wave * 32 + r8) * Kq + cbl * 8;
  const unsigned short* gB = BT + (size_t)(col0 + wave * 32 + r8) * Kq + cbl * 8;

  f32x4 acc[4][4];
#pragma unroll
  for (int i = 0; i < 4; i++)
#pragma unroll
    for (int j = 0; j < 4; j++) acc[i][j] = (f32x4){0.f, 0.f, 0.f, 0.f};

  for (int k0 = 0; k0 < Kq; k0 += 64) {
    __syncthreads();
#pragma unroll
    for (int i = 0; i < 4; ++i) {
      glds16(gA + (size_t)(i * 8) * Kq + k0, &As[(wave * 32 + i * 8) * 64]);
      glds16(gB + (size_t)(i * 8) * Kq + k0, &Bs[(wave * 32 + i * 8) * 64]);
    }
    __syncthreads();
#pragma unroll
    for (int kk = 0; kk < 64; kk += 32) {
      short8 af[4], bfr[4];
#pragma unroll
      for (int t = 0; t < 4; t++) {
        int row = wm * 64 + t * 16 + l16;
        int cb = (kk >> 3) + ql;
        af[t] = *(const short8*)&As[row * 64 + ((cb ^ (row & 7)) << 3)];
      }
#pragma unroll
      for (int t = 0; t < 4; t++) {
        int row = wn * 64 + t * 16 + l16;
        int cb = (kk >> 3) + ql;
        bfr[t] = *(const short8*)&Bs[row * 64 + ((cb ^ (row & 7)) << 3)];
      }
#pragma unroll
      for (int i = 0; i < 4; i++)
#pragma unroll
        for (int j = 0; j < 4; j++) acc[i][j] = mfma16(af[i], bfr[j], acc[i][j]);
    }
  }
#pragma unroll
  for (int i = 0; i < 4; i++)
#pragma unroll
    for (int j = 0; j < 4; j++)
#pragma unroll
      for (int r = 0; r < 4; r++) {
        int rr = row0 + wm * 64 + i * 16 + ql * 4 + r;
        int cc = col0 + wn * 64 + j * 16 + l16;
        Cout[(size_t)rr * Nq + cc] = acc[i][j][r];
      }
}

// ---------------- per-head normalize -> fp16 (QG/KV now fp16 in) ----------------
__global__ __launch_bounds__(256) void norm_kernel(const unsigned short* __restrict__ QG,
                                                   const unsigned short* __restrict__ KV,
                                                   unsigned short* __restrict__ Qn,   // fp16 [bh][n][16]
                                                   unsigned short* __restrict__ Kn,   // fp16 [bh][n][16]
                                                   unsigned short* __restrict__ Vtg)  // fp16 [bh][d][n]
{
  int g = blockIdx.x * 256 + threadIdx.x;
  int n = g & (Nc - 1), bh = g >> 11;
  int h = bh & 15, b = bh >> 4;
  size_t src = ((size_t)(b * Nc + n)) * DIc + h * 80;

  {
    half8 u0 = *(const half8*)&QG[src];
    half8 u1 = *(const half8*)&QG[src + 8];
    float q[16], ss = 0.f;
#pragma unroll
    for (int i = 0; i < 8; i++) { q[i] = (float)u0[i]; q[8 + i] = (float)u1[i]; }
#pragma unroll
    for (int i = 0; i < 16; i++) ss += q[i] * q[i];
    float sc = 1.f / fmaxf(sqrtf(ss), 1e-12f);
    half8 o0, o1;
#pragma unroll
    for (int i = 0; i < 8; i++) { o0[i] = (_Float16)(q[i] * sc); o1[i] = (_Float16)(q[8 + i] * sc); }
    size_t dst = ((size_t)bh * Nc + n) * 16;
    *(half8*)&Qn[dst] = o0;
    *(half8*)&Qn[dst + 8] = o1;
  }
  {
    half8 u0 = *(const half8*)&KV[src];
    half8 u1 = *(const half8*)&KV[src + 8];
    float q[16], ss = 0.f;
#pragma unroll
    for (int i = 0; i < 8; i++) { q[i] = (float)u0[i]; q[8 + i] = (float)u1[i]; }
#pragma unroll
    for (int i = 0; i < 16; i++) ss += q[i] * q[i];
    float sc = 1.f / fmaxf(sqrtf(ss), 1e-12f);
    half8 o0, o1;
#pragma unroll
    for (int i = 0; i < 8; i++) { o0[i] = (_Float16)(q[i] * sc); o1[i] = (_Float16)(q[8 + i] * sc); }
    size_t dst = ((size_t)bh * Nc + n) * 16;
    *(half8*)&Kn[dst] = o0;
    *(half8*)&Kn[dst + 8] = o1;
  }
  {
    half8 u[8];
#pragma unroll
    for (int i = 0; i < 8; i++) u[i] = *(const half8*)&KV[src + 16 + i * 8];
    float ss = 0.f;
#pragma unroll
    for (int i = 0; i < 8; i++)
#pragma unroll
      for (int j = 0; j < 8; j++) { float x = (float)u[i][j]; ss += x * x; }
    float sc = 1.f / fmaxf(sqrtf(ss), 1e-12f);
#pragma unroll
    for (int i = 0; i < 8; i++)
#pragma unroll
      for (int j = 0; j < 8; j++) {
        int d = i * 8 + j;
        union { _Float16 h; unsigned short us; } cv;
        cv.h = (_Float16)((float)u[i][j] * sc);
        Vtg[((size_t)bh * DVc + d) * Nc + n] = cv.us;
      }
  }
}

// ---------------- relu^2 attention, fp16 datapath ----------------
// R8 structure (verified 68.1us): async glds16 V staging (benign 2-way read
// conflict), K=16 S-MFMA, kf register double-buffer, unpadded 16-wide Qn/Kn,
// setprio around PV. R10: gate slice of QG is now fp16 (decode change only).
__global__ __launch_bounds__(256, 4) void attn_kernel(const unsigned short* __restrict__ Qn,
                                                      const unsigned short* __restrict__ Kn,
                                                      const unsigned short* __restrict__ Vtg,
                                                      const unsigned short* __restrict__ QG,
                                                      unsigned short* __restrict__ outpre) {
  __shared__ unsigned short shm[2 * 64 * 128];  // vt[2][64][128] fp16 (32KB); epilogue aliases of[128][68]

  int gid = blockIdx.x;
  int xcd = gid & 7, slot = gid >> 3;
  int bh = xcd * 8 + (slot & 7);
  int q0 = (slot >> 3) * 128;
  int b = bh >> 4, h = bh & 15;
  int tid = threadIdx.x, lane = tid & 63, wave = tid >> 6;
  int ql = lane >> 4, l16 = lane & 15;
  int qw0 = q0 + wave * 32;

  // Q fragments (B-operand of S-mfma, K=16), resident: q = qw0 + qt*16 + l16
  half4 qf[2];
#pragma unroll
  for (int qt = 0; qt < 2; ++qt)
    qf[qt] = *(const half4*)&Qn[((size_t)bh * Nc + qw0 + qt * 16 + l16) * 16 + ql * 4];

  const unsigned short* krow = Kn + (size_t)bh * Nc * 16;
  const unsigned short* vbase = Vtg + ((size_t)bh * DVc) * Nc;

  int lq = lane >> 4, m16 = lane & 15;

  f32x4 acc[4][2];
#pragma unroll
  for (int dt = 0; dt < 4; dt++) { acc[dt][0] = (f32x4){0.f,0.f,0.f,0.f}; acc[dt][1] = (f32x4){0.f,0.f,0.f,0.f}; }

  half4 kfA[8], kfB[8];

  // ---- prologue: kf tile 0 -> kfA; V tile 0 -> buf0 via async glds16 ----
#pragma unroll
  for (int kh = 0; kh < 8; ++kh)
    kfA[kh] = *(const half4*)&krow[(size_t)(kh * 16 + l16) * 16 + ql * 4];
#pragma unroll
  for (int i = 0; i < 4; ++i) {
    int r0 = i * 16 + wave * 4;
    int d = r0 + lq;
    glds16(vbase + (size_t)d * Nc + 0 + ((m16 ^ (d & 7)) << 3), &shm[r0 * 128]);
  }

#define TILE_BODY(KT, KFU, KFN, LN)                                                      \
  {                                                                                      \
    __syncthreads(); /* drains glds for this tile; all waves done reading prev buf */    \
    unsigned short* vtb = &shm[((KT) & 1) * 8192];                                       \
    if (LN) {                                                                            \
      int kn0 = ((KT) + 1) * 128;                                                        \
      unsigned short* nb = &shm[(((KT) + 1) & 1) * 8192];                                \
      _Pragma("unroll") for (int i = 0; i < 4; ++i) {                                    \
        int r0 = i * 16 + wave * 4;                                                      \
        int d = r0 + lq;                                                                 \
        glds16(vbase + (size_t)d * Nc + kn0 + ((m16 ^ (d & 7)) << 3), &nb[r0 * 128]);    \
      }                                                                                  \
      _Pragma("unroll") for (int kh = 0; kh < 8; ++kh)                                   \
        KFN[kh] = *(const half4*)&krow[(size_t)(kn0 + kh * 16 + l16) * 16 + ql * 4];     \
    }                                                                                    \
    _Pragma("unroll") for (int p = 0; p < 4; ++p) { /* 32-key group */                   \
      f32x4 c0[2], c1[2];                                                                \
      _Pragma("unroll") for (int qt = 0; qt < 2; ++qt) {                                 \
        c0[qt] = mfma16k(KFU[2 * p],     qf[qt], (f32x4){0.f, 0.f, 0.f, 0.f});           \
        c1[qt] = mfma16k(KFU[2 * p + 1], qf[qt], (f32x4){0.f, 0.f, 0.f, 0.f});           \
      }                                                                                  \
      half8 pf[2];                                                                       \
      _Pragma("unroll") for (int qt = 0; qt < 2; ++qt) {                                 \
        union { half8 hh; fp16x2 p2[4]; } w;                                             \
        fp16x2 t0 = __builtin_amdgcn_cvt_pkrtz(c0[qt][0], c0[qt][1]);                    \
        fp16x2 t1 = __builtin_amdgcn_cvt_pkrtz(c0[qt][2], c0[qt][3]);                    \
        fp16x2 t2 = __builtin_amdgcn_cvt_pkrtz(c1[qt][0], c1[qt][1]);                    \
        fp16x2 t3 = __builtin_amdgcn_cvt_pkrtz(c1[qt][2], c1[qt][3]);                    \
        const fp16x2 hz = {(__fp16)0, (__fp16)0};                                        \
        t0 = __builtin_elementwise_max(t0, hz); w.p2[0] = t0 * t0;                       \
        t1 = __builtin_elementwise_max(t1, hz); w.p2[1] = t1 * t1;                       \
        t2 = __builtin_elementwise_max(t2, hz); w.p2[2] = t2 * t2;                       \
        t3 = __builtin_elementwise_max(t3, hz); w.p2[3] = t3 * t3;                       \
        pf[qt] = w.hh;                                                                   \
      }                                                                                  \
      /* PV: A = V^T frags from LDS (16B-granule swizzle, permuted key order) */         \
      int tsw = (l16 & 7) << 1;                                                          \
      int s1 = ((p * 8 + ql) ^ tsw) << 2;                                                \
      int s2 = ((p * 8 + 4 + ql) ^ tsw) << 2;                                            \
      __builtin_amdgcn_s_setprio(1);                                                     \
      _Pragma("unroll") for (int dt = 0; dt < 4; ++dt) {                                 \
        const unsigned short* vrow = vtb + (dt * 16 + l16) * 128;                        \
        union { half8 s; uint4 u; } vf;                                                  \
        uint2 va = *(const uint2*)&vrow[s1];                                             \
        uint2 vb2 = *(const uint2*)&vrow[s2];                                            \
        vf.u.x = va.x; vf.u.y = va.y; vf.u.z = vb2.x; vf.u.w = vb2.y;                    \
        _Pragma("unroll") for (int qt = 0; qt < 2; ++qt)                                 \
          acc[dt][qt] = mfma16h(vf.s, pf[qt], acc[dt][qt]);                              \
      }                                                                                  \
      __builtin_amdgcn_s_setprio(0);                                                     \
    }                                                                                    \
  }

#pragma unroll 1
  for (int kt2 = 0; kt2 < 8; ++kt2) {
    int kte = kt2 * 2;
    TILE_BODY(kte, kfA, kfB, 1)
    TILE_BODY(kte + 1, kfB, kfA, (kt2 < 7))
  }
#undef TILE_BODY

  __syncthreads();  // all waves done with vt before 'of' aliases shm
  unsigned short(*of)[68] = (unsigned short(*)[68])shm;

  // epilogue: lane(ql,l16) holds O[q = qt*16+l16 (local)][d = dt*16+ql*4+r]
#pragma unroll
  for (int qt = 0; qt < 2; ++qt) {
    float ss = 0.f;
#pragma unroll
    for (int dt = 0; dt < 4; ++dt)
#pragma unroll
      for (int r = 0; r < 4; ++r) { float v = acc[dt][qt][r]; ss += v * v; }
    ss += __shfl_xor(ss, 16, 64);
    ss += __shfl_xor(ss, 32, 64);
    float nrm = sqrtf(ss);
    float sc = tanhf(nrm) / fmaxf(nrm, 1e-12f);
    int q = qw0 + qt * 16 + l16;
    size_t gbase = ((size_t)(b * Nc + q)) * DIc + h * 80 + DKc;  // gate slice of QG (fp16)
#pragma unroll
    for (int dt = 0; dt < 4; ++dt) {
      uint2 gu = *(const uint2*)&QG[gbase + dt * 16 + ql * 4];
      union { uint2 u; _Float16 h[4]; } gv; gv.u = gu;
      float o[4];
#pragma unroll
      for (int r = 0; r < 4; ++r) {
        float x = (float)gv.h[r];
        float s = x / (1.f + __expf(-x));
        float e2 = __expf(2.f * s);
        float g = 1.f - 2.f / (e2 + 1.f);  // tanh(s)
        o[r] = acc[dt][qt][r] * sc * g;
      }
      uint2 w;
      w.x = pack2bf(o[0], o[1]);
      w.y = pack2bf(o[2], o[3]);
      *(uint2*)&of[wave * 32 + qt * 16 + l16][dt * 16 + ql * 4] = w;
    }
  }
  __syncthreads();
  {
    int row = tid >> 1, cb = (tid & 1) * 32;
    size_t obase = ((size_t)(b * Nc + q0 + row)) * (Hc * DVc) + h * DVc + cb;
#pragma unroll
    for (int i = 0; i < 4; ++i)
      *(ushort8*)&outpre[obase + i * 8] = *(const ushort8*)&of[row][cb + i * 8];
  }
}

extern "C" void kernel_launch(void* const* d_in, const int* in_sizes, int n_in,
                              void* d_out, int out_size, void* d_ws, size_t ws_size,
                              hipStream_t stream) {
  const float* X = (const float*)d_in[0];     // (4,2048,1024)
  const float* Wqg = (const float*)d_in[1];   // (1024,1280)
  const float* Wkv = (const float*)d_in[2];   // (1024,1280)
  const float* Wout = (const float*)d_in[3];  // (1024,1024)
  float* out = (float*)d_out;
  (void)in_sizes; (void)n_in; (void)out_size; (void)ws_size;

  char* ws = (char*)d_ws;
  size_t off = 0;
  auto alloc = [&](size_t bytes) {
    void* p = ws + off;
    off += (bytes + 255) & ~(size_t)255;
    return p;
  };
  unsigned short* Xbf   = (unsigned short*)alloc((size_t)Mc * Dc * 2);            // 16 MB
  unsigned short* WqgT  = (unsigned short*)alloc((size_t)DIc * Dc * 2);           // 2.5 MB (WkvT MUST follow contiguously)
  unsigned short* WkvT  = (unsigned short*)alloc((size_t)DIc * Dc * 2);
  unsigned short* WoutT = (unsigned short*)alloc((size_t)Dc * Dc * 2);            // 2 MB
  unsigned short* QG    = (unsigned short*)alloc((size_t)Mc * DIc * 2);           // 20 MB (fp16)
  unsigned short* KV    = (unsigned short*)alloc((size_t)Mc * DIc * 2);           // 20 MB (fp16)
  unsigned short* Qn    = (unsigned short*)alloc((size_t)Bc * Hc * Nc * 16 * 2);  // 4 MB (fp16, unpadded)
  unsigned short* Kn    = (unsigned short*)alloc((size_t)Bc * Hc * Nc * 16 * 2);  // 4 MB
  unsigned short* Vtg   = (unsigned short*)alloc((size_t)Bc * Hc * Nc * DVc * 2); // 16 MB (fp16)
  unsigned short* outpre = Xbf;  // Xbf dead after projection GEMM; same size

  prep_kernel<<<4992, 256, 0, stream>>>(X, Xbf, Wqg, WqgT, Wkv, WkvT, Wout, WoutT);
  gemm_proj<<<Mc / 128 * (2 * DIc / 128), 256, 0, stream>>>(Xbf, WqgT, QG, KV, Dc);
  norm_kernel<<<(Mc * Hc) / 256, 256, 0, stream>>>(QG, KV, Qn, Kn, Vtg);
  attn_kernel<<<1024, 256, 0, stream>>>(Qn, Kn, Vtg, QG, outpre);
  gemm_glds<<<Mc / 128 * (Dc / 128), 256, 0, stream>>>(outpre, WoutT, out, Mc, Dc, Dc);
}